// Round 5
// baseline (266.989 us; speedup 1.0000x reference)
//
#include <hip/hip_runtime.h>
#include <math.h>

// B=256, A=16 -> N=4096 tokens; EMBED=HIDDEN=1024, PROJ=256.
// fp32 GEMMs emulated via bf16 hi/lo split MFMA (3 terms: Ah*Bh + Ah*Bl + Al*Bh).
// This round: k-chunk-major LDS [kb][row][8] (conflict-free b128, linear),
// global_load_lds width-16 staging, double-buffered 2-phase pipeline
// (stage next || compute cur, one __syncthreads per K-step).
// d_out: z [4096*256] | loss [1] | logits [4096*4096]  (fp32)
// d_ws layout (30,408,712 B; aliased lifetimes disjoint):
//   [0,8M) Hh | [8M,16M) Hl | [16M,20M) W1t (dead after g1) / [16M,24M) P
//   | [24M..25M) W2t | [25M,27M) Zbh | [27M,29M) Zbl | acc 8B

#define NTOK 4096
#define DEMB 1024
#define DHID 1024
#define DPRJ 256

typedef __attribute__((ext_vector_type(8))) short bf16x8;
typedef __attribute__((ext_vector_type(4))) float f32x4;

typedef __attribute__((address_space(3))) void lds_void_t;
typedef __attribute__((address_space(1))) const void gbl_void_t;

static __device__ __forceinline__ void glds16(const void* g, void* l) {
    __builtin_amdgcn_global_load_lds((gbl_void_t*)g, (lds_void_t*)l, 16, 0, 0);
}

// truncating hi/lo bf16 split: v ~= hi + lo, residual ~2^-16 relative
static __device__ __forceinline__ void split2(float v, ushort* h, ushort* l) {
    const uint u = __float_as_uint(v);
    *h = (ushort)(u >> 16);
    const float r = v - __uint_as_float(u & 0xffff0000u);
    *l = (ushort)(__float_as_uint(r) >> 16);
}
// exact-GELU via A&S 7.1.26 rational erf (|err| <= 1.5e-7), hardware exp
static __device__ __forceinline__ float gelu_fast(float v) {
    const float x  = v * 0.70710678118654752440f;
    const float ax = fabsf(x);
    const float t  = 1.0f / (1.0f + 0.3275911f * ax);
    const float poly = t * (0.254829592f + t * (-0.284496736f + t * (1.421413741f
                     + t * (-1.453152027f + t * 1.061405429f))));
    const float erf_ax = 1.0f - poly * __expf(-ax * ax);
    return 0.5f * v * (1.0f + copysignf(erf_ax, x));
}
static __device__ __forceinline__ float log_sigmoid_fast(float x) {
    return fminf(x, 0.0f) - __logf(1.0f + __expf(-fabsf(x)));
}

// ---------------------------------------------------------------------------
// Tiled transpose+convert: fp32 [K][N] -> bf16 hi/lo [N][K]. 32x32 tiles.
// ---------------------------------------------------------------------------
__global__ __launch_bounds__(256)
void k_cvt_T(const float* __restrict__ W, ushort* __restrict__ WtH,
             ushort* __restrict__ WtL, int K, int N)
{
    __shared__ float tile[32][33];
    const int tn0 = blockIdx.x * 32;
    const int tk0 = blockIdx.y * 32;
    const int tr = threadIdx.x >> 5;
    const int tc = threadIdx.x & 31;
#pragma unroll
    for (int p = 0; p < 4; ++p)
        tile[tr + 8 * p][tc] = W[(size_t)(tk0 + tr + 8 * p) * N + tn0 + tc];
    __syncthreads();
#pragma unroll
    for (int p = 0; p < 4; ++p) {
        const int n = tr + 8 * p;
        ushort h, l;
        split2(tile[tc][n], &h, &l);
        WtH[(size_t)(tn0 + n) * K + tk0 + tc] = h;
        WtL[(size_t)(tn0 + n) * K + tk0 + tc] = l;
    }
}

// ---------------------------------------------------------------------------
// GEMM1: H = gelu(X @ W1 + b1) -> bf16 hi/lo.  BM=128, BN=64, BK=32, grid 512.
// LDS buffer (u16): Ah[4][128][8] | Al | Bh[4][64][8] | Bl  = 12288 u16, x2 dbuf.
// A: fp32 reg-load early -> convert -> ds_write late.  B: global_load_lds.
// ---------------------------------------------------------------------------
#define G1_BUF 12288
__global__ __launch_bounds__(256, 3)
void k_gemm1(const float* __restrict__ X,
             const ushort* __restrict__ W1tH, const ushort* __restrict__ W1tL,
             const float* __restrict__ B1,
             ushort* __restrict__ Hh, ushort* __restrict__ Hl)
{
    __shared__ __align__(16) ushort sm[2 * G1_BUF];
    const int t = threadIdx.x, lane = t & 63, w = t >> 6;
    const int wr = w >> 1, wc = w & 1;
    const int bm = blockIdx.x * 128, bn = blockIdx.y * 64;
    const int kb = lane >> 4, lr = lane & 15;

    // A: thread loads rows (bm+ar, bm+ar+64), k-seg w (8 floats each)
    const int ar = t & 63;
    const float* xp0 = X + (size_t)(bm + ar) * DEMB + w * 8;
    const float* xp1 = xp0 + (size_t)64 * DEMB;
    // B: wave w stages k-chunk w, row = lane
    const ushort* bhs = W1tH + (size_t)(bn + lane) * DEMB + w * 8;
    const ushort* bls = W1tL + (size_t)(bn + lane) * DEMB + w * 8;

    f32x4 acc[4][2];
#pragma unroll
    for (int i = 0; i < 4; ++i)
#pragma unroll
        for (int j = 0; j < 2; ++j) acc[i][j] = (f32x4){0.f, 0.f, 0.f, 0.f};

    // ---- prologue: stage k-step 0 into buf0
    {
        const float4 a00 = *(const float4*)(xp0);
        const float4 a01 = *(const float4*)(xp0 + 4);
        const float4 a10 = *(const float4*)(xp1);
        const float4 a11 = *(const float4*)(xp1 + 4);
        glds16(bhs, sm + 8192 + w * 512);
        glds16(bls, sm + 10240 + w * 512);
        const float va[8] = {a00.x, a00.y, a00.z, a00.w, a01.x, a01.y, a01.z, a01.w};
        const float vb[8] = {a10.x, a10.y, a10.z, a10.w, a11.x, a11.y, a11.z, a11.w};
        uint4 h0, l0, h1, l1;
#pragma unroll
        for (int e = 0; e < 8; ++e) {
            split2(va[e], (ushort*)&h0 + e, (ushort*)&l0 + e);
            split2(vb[e], (ushort*)&h1 + e, (ushort*)&l1 + e);
        }
        *(uint4*)(sm + w * 1024 + ar * 8)               = h0;
        *(uint4*)(sm + 4096 + w * 1024 + ar * 8)        = l0;
        *(uint4*)(sm + w * 1024 + (ar + 64) * 8)        = h1;
        *(uint4*)(sm + 4096 + w * 1024 + (ar + 64) * 8) = l1;
        __syncthreads();
    }

    int co = 0;
#pragma unroll 2
    for (int ks = 0; ks < 32; ++ks) {
        float4 a00, a01, a10, a11;
        if (ks < 31) {
            const int kt = (ks + 1) * 32;
            a00 = *(const float4*)(xp0 + kt);
            a01 = *(const float4*)(xp0 + kt + 4);
            a10 = *(const float4*)(xp1 + kt);
            a11 = *(const float4*)(xp1 + kt + 4);
            ushort* nb = sm + (co ^ G1_BUF);
            glds16(bhs + kt, nb + 8192 + w * 512);
            glds16(bls + kt, nb + 10240 + w * 512);
        }
        const ushort* cb = sm + co;
        bf16x8 bh[2], bl[2];
#pragma unroll
        for (int j = 0; j < 2; ++j) {
            const int o = kb * 512 + (wc * 32 + j * 16 + lr) * 8;
            bh[j] = *(const bf16x8*)(cb + 8192 + o);
            bl[j] = *(const bf16x8*)(cb + 10240 + o);
        }
#pragma unroll
        for (int i = 0; i < 4; ++i) {
            const int o = kb * 1024 + (wr * 64 + i * 16 + lr) * 8;
            const bf16x8 ah = *(const bf16x8*)(cb + o);
            const bf16x8 al = *(const bf16x8*)(cb + 4096 + o);
#pragma unroll
            for (int j = 0; j < 2; ++j) {
                acc[i][j] = __builtin_amdgcn_mfma_f32_16x16x32_bf16(ah, bh[j], acc[i][j], 0, 0, 0);
                acc[i][j] = __builtin_amdgcn_mfma_f32_16x16x32_bf16(ah, bl[j], acc[i][j], 0, 0, 0);
                acc[i][j] = __builtin_amdgcn_mfma_f32_16x16x32_bf16(al, bh[j], acc[i][j], 0, 0, 0);
            }
        }
        if (ks < 31) {
            ushort* nb = sm + (co ^ G1_BUF);
            const float va[8] = {a00.x, a00.y, a00.z, a00.w, a01.x, a01.y, a01.z, a01.w};
            const float vb[8] = {a10.x, a10.y, a10.z, a10.w, a11.x, a11.y, a11.z, a11.w};
            uint4 h0, l0, h1, l1;
#pragma unroll
            for (int e = 0; e < 8; ++e) {
                split2(va[e], (ushort*)&h0 + e, (ushort*)&l0 + e);
                split2(vb[e], (ushort*)&h1 + e, (ushort*)&l1 + e);
            }
            *(uint4*)(nb + w * 1024 + ar * 8)               = h0;
            *(uint4*)(nb + 4096 + w * 1024 + ar * 8)        = l0;
            *(uint4*)(nb + w * 1024 + (ar + 64) * 8)        = h1;
            *(uint4*)(nb + 4096 + w * 1024 + (ar + 64) * 8) = l1;
        }
        __syncthreads();
        co ^= G1_BUF;
    }

    // epilogue: bias + gelu -> bf16 hi/lo H
#pragma unroll
    for (int j = 0; j < 2; ++j) {
        const int col = bn + wc * 32 + j * 16 + lr;
        const float b = B1[col];
#pragma unroll
        for (int i = 0; i < 4; ++i) {
#pragma unroll
            for (int e = 0; e < 4; ++e) {
                const int row = bm + wr * 64 + i * 16 + kb * 4 + e;
                const float g = gelu_fast(acc[i][j][e] + b);
                ushort h, l;
                split2(g, &h, &l);
                Hh[(size_t)row * DHID + col] = h;
                Hl[(size_t)row * DHID + col] = l;
            }
        }
    }
}

// ---------------------------------------------------------------------------
// GEMM2 (split-K x2): P[kz] = H @ W2 over K-half. BM=128, BN=64, grid 256.
// All-u16 staging via global_load_lds; same LDS geometry as gemm1.
// ---------------------------------------------------------------------------
#define G2_BUF 12288
__global__ __launch_bounds__(256, 3)
void k_gemm2(const ushort* __restrict__ Hh, const ushort* __restrict__ Hl,
             const ushort* __restrict__ W2tH, const ushort* __restrict__ W2tL,
             float* __restrict__ P)
{
    __shared__ __align__(16) ushort sm[2 * G2_BUF];
    const int t = threadIdx.x, lane = t & 63, w = t >> 6;
    const int wr = w >> 1, wc = w & 1;
    const int bm = blockIdx.x * 128, bn = blockIdx.y * 64;
    const int k0 = blockIdx.z * 512;
    const int kb = lane >> 4, lr = lane & 15;

    const ushort* ah0 = Hh + (size_t)(bm + lane) * DHID + k0 + w * 8;
    const ushort* ah1 = Hh + (size_t)(bm + 64 + lane) * DHID + k0 + w * 8;
    const ushort* al0 = Hl + (size_t)(bm + lane) * DHID + k0 + w * 8;
    const ushort* al1 = Hl + (size_t)(bm + 64 + lane) * DHID + k0 + w * 8;
    const ushort* bhs = W2tH + (size_t)(bn + lane) * DHID + k0 + w * 8;
    const ushort* bls = W2tL + (size_t)(bn + lane) * DHID + k0 + w * 8;

    f32x4 acc[4][2];
#pragma unroll
    for (int i = 0; i < 4; ++i)
#pragma unroll
        for (int j = 0; j < 2; ++j) acc[i][j] = (f32x4){0.f, 0.f, 0.f, 0.f};

#define G2_STAGE(buf, kt)                                   \
    glds16(ah0 + (kt), (buf) + w * 1024);                   \
    glds16(ah1 + (kt), (buf) + w * 1024 + 512);             \
    glds16(al0 + (kt), (buf) + 4096 + w * 1024);            \
    glds16(al1 + (kt), (buf) + 4096 + w * 1024 + 512);      \
    glds16(bhs + (kt), (buf) + 8192 + w * 512);             \
    glds16(bls + (kt), (buf) + 10240 + w * 512);

    { G2_STAGE(sm, 0); __syncthreads(); }

    int co = 0;
#pragma unroll 2
    for (int ks = 0; ks < 16; ++ks) {
        if (ks < 15) {
            ushort* nb = sm + (co ^ G2_BUF);
            const int kt = (ks + 1) * 32;
            G2_STAGE(nb, kt);
        }
        const ushort* cb = sm + co;
        bf16x8 bh[2], bl[2];
#pragma unroll
        for (int j = 0; j < 2; ++j) {
            const int o = kb * 512 + (wc * 32 + j * 16 + lr) * 8;
            bh[j] = *(const bf16x8*)(cb + 8192 + o);
            bl[j] = *(const bf16x8*)(cb + 10240 + o);
        }
#pragma unroll
        for (int i = 0; i < 4; ++i) {
            const int o = kb * 1024 + (wr * 64 + i * 16 + lr) * 8;
            const bf16x8 ah = *(const bf16x8*)(cb + o);
            const bf16x8 al = *(const bf16x8*)(cb + 4096 + o);
#pragma unroll
            for (int j = 0; j < 2; ++j) {
                acc[i][j] = __builtin_amdgcn_mfma_f32_16x16x32_bf16(ah, bh[j], acc[i][j], 0, 0, 0);
                acc[i][j] = __builtin_amdgcn_mfma_f32_16x16x32_bf16(ah, bl[j], acc[i][j], 0, 0, 0);
                acc[i][j] = __builtin_amdgcn_mfma_f32_16x16x32_bf16(al, bh[j], acc[i][j], 0, 0, 0);
            }
        }
        __syncthreads();
        co ^= G2_BUF;
    }

    float* Pz = P + (size_t)blockIdx.z * NTOK * DPRJ;
#pragma unroll
    for (int j = 0; j < 2; ++j) {
        const int col = bn + wc * 32 + j * 16 + lr;
#pragma unroll
        for (int i = 0; i < 4; ++i) {
#pragma unroll
            for (int e = 0; e < 4; ++e) {
                const int row = bm + wr * 64 + i * 16 + kb * 4 + e;
                Pz[(size_t)row * DPRJ + col] = acc[i][j][e];
            }
        }
    }
}

// ---------------------------------------------------------------------------
// Row normalize: p = P0+P1+b2; z = p/||p||. Emits z fp32 + bf16 hi/lo; zeroes acc.
// ---------------------------------------------------------------------------
__global__ __launch_bounds__(256)
void k_norm(const float* __restrict__ P, const float* __restrict__ B2,
            float* __restrict__ Zo, ushort* __restrict__ Zbh,
            ushort* __restrict__ Zbl, double* __restrict__ lossacc)
{
    const int r = blockIdx.x;
    const int c = threadIdx.x;
    if (r == 0 && c == 0) *lossacc = 0.0;   // completes before k_gemm3 (stream order)

    const float v = P[(size_t)r * DPRJ + c]
                  + P[(size_t)NTOK * DPRJ + (size_t)r * DPRJ + c] + B2[c];
    float ss = v * v;
#pragma unroll
    for (int o = 32; o > 0; o >>= 1) ss += __shfl_down(ss, o);
    __shared__ float wsum[4];
    if ((c & 63) == 0) wsum[c >> 6] = ss;
    __syncthreads();
    const float tot = wsum[0] + wsum[1] + wsum[2] + wsum[3];
    const float z = v / sqrtf(tot);
    Zo[(size_t)r * DPRJ + c] = z;
    ushort h, l;
    split2(z, &h, &l);
    Zbh[(size_t)r * DPRJ + c] = h;
    Zbl[(size_t)r * DPRJ + c] = l;
}

// ---------------------------------------------------------------------------
// GEMM3: logits = (Z @ Z^T)*scale + bias, fused fast log-sigmoid loss.
// BM=BN=128, K=256 (8 k-steps), grid 1024. All staging via global_load_lds,
// dbuf 2-phase. LDS buffer: Ah[4][128][8] | Al | Bh | Bl = 16384 u16, x2.
// ---------------------------------------------------------------------------
#define G3_BUF 16384
__global__ __launch_bounds__(256, 2)
void k_gemm3(const ushort* __restrict__ Zbh, const ushort* __restrict__ Zbl,
             const float* __restrict__ LS, const float* __restrict__ LB,
             float* __restrict__ Lg, double* __restrict__ lossacc)
{
    __shared__ __align__(16) ushort sm[2 * G3_BUF];   // 64 KB
    const int t = threadIdx.x, lane = t & 63, w = t >> 6;
    const int wr = w >> 1, wc = w & 1;
    const int bm = blockIdx.x * 128, bn = blockIdx.y * 128;
    const int kb = lane >> 4, lr = lane & 15;

    const ushort* aH0 = Zbh + (size_t)(bm + lane) * DPRJ + w * 8;
    const ushort* aH1 = Zbh + (size_t)(bm + 64 + lane) * DPRJ + w * 8;
    const ushort* aL0 = Zbl + (size_t)(bm + lane) * DPRJ + w * 8;
    const ushort* aL1 = Zbl + (size_t)(bm + 64 + lane) * DPRJ + w * 8;
    const ushort* bH0 = Zbh + (size_t)(bn + lane) * DPRJ + w * 8;
    const ushort* bH1 = Zbh + (size_t)(bn + 64 + lane) * DPRJ + w * 8;
    const ushort* bL0 = Zbl + (size_t)(bn + lane) * DPRJ + w * 8;
    const ushort* bL1 = Zbl + (size_t)(bn + 64 + lane) * DPRJ + w * 8;

    f32x4 acc[4][4];
#pragma unroll
    for (int i = 0; i < 4; ++i)
#pragma unroll
        for (int j = 0; j < 4; ++j) acc[i][j] = (f32x4){0.f, 0.f, 0.f, 0.f};

#define G3_STAGE(buf, kt)                                    \
    glds16(aH0 + (kt), (buf) + w * 1024);                    \
    glds16(aH1 + (kt), (buf) + w * 1024 + 512);              \
    glds16(aL0 + (kt), (buf) + 4096 + w * 1024);             \
    glds16(aL1 + (kt), (buf) + 4096 + w * 1024 + 512);       \
    glds16(bH0 + (kt), (buf) + 8192 + w * 1024);             \
    glds16(bH1 + (kt), (buf) + 8192 + w * 1024 + 512);       \
    glds16(bL0 + (kt), (buf) + 12288 + w * 1024);            \
    glds16(bL1 + (kt), (buf) + 12288 + w * 1024 + 512);

    { G3_STAGE(sm, 0); __syncthreads(); }

    int co = 0;
#pragma unroll
    for (int ks = 0; ks < 8; ++ks) {
        if (ks < 7) {
            ushort* nb = sm + (co ^ G3_BUF);
            const int kt = (ks + 1) * 32;
            G3_STAGE(nb, kt);
        }
        const ushort* cb = sm + co;
        bf16x8 bh[4], bl[4];
#pragma unroll
        for (int j = 0; j < 4; ++j) {
            const int o = kb * 1024 + (wc * 64 + j * 16 + lr) * 8;
            bh[j] = *(const bf16x8*)(cb + 8192 + o);
            bl[j] = *(const bf16x8*)(cb + 12288 + o);
        }
#pragma unroll
        for (int i = 0; i < 4; ++i) {
            const int o = kb * 1024 + (wr * 64 + i * 16 + lr) * 8;
            const bf16x8 ah = *(const bf16x8*)(cb + o);
            const bf16x8 al = *(const bf16x8*)(cb + 4096 + o);
#pragma unroll
            for (int j = 0; j < 4; ++j) {
                acc[i][j] = __builtin_amdgcn_mfma_f32_16x16x32_bf16(ah, bh[j], acc[i][j], 0, 0, 0);
                acc[i][j] = __builtin_amdgcn_mfma_f32_16x16x32_bf16(ah, bl[j], acc[i][j], 0, 0, 0);
                acc[i][j] = __builtin_amdgcn_mfma_f32_16x16x32_bf16(al, bh[j], acc[i][j], 0, 0, 0);
            }
        }
        __syncthreads();
        co ^= G3_BUF;
    }

    const float scale = __expf(LS[0]);
    const float lbias = LB[0];
    float lsum = 0.0f;
#pragma unroll
    for (int j = 0; j < 4; ++j) {
        const int col = bn + wc * 64 + j * 16 + lr;
        const int cid = col >> 4;
#pragma unroll
        for (int i = 0; i < 4; ++i) {
#pragma unroll
            for (int e = 0; e < 4; ++e) {
                const int row = bm + wr * 64 + i * 16 + kb * 4 + e;
                const float lg = fmaf(acc[i][j][e], scale, lbias);
                __builtin_nontemporal_store(lg, &Lg[(size_t)row * NTOK + col]);
                const float x = ((row >> 4) == cid) ? lg : -lg;
                lsum += log_sigmoid_fast(x);
            }
        }
    }

#pragma unroll
    for (int o = 32; o > 0; o >>= 1) lsum += __shfl_down(lsum, o);
    __shared__ float wsum[4];
    if ((t & 63) == 0) wsum[t >> 6] = lsum;
    __syncthreads();
    if (t == 0) {
        const double bs = (double)wsum[0] + (double)wsum[1]
                        + (double)wsum[2] + (double)wsum[3];
        atomicAdd(lossacc, bs);
    }
}

__global__ void k_finalize(const double* __restrict__ lossacc,
                           float* __restrict__ loss_out)
{
    loss_out[0] = (float)(-(*lossacc) / (double)NTOK);
}

// ---------------------------------------------------------------------------
extern "C" void kernel_launch(void* const* d_in, const int* in_sizes, int n_in,
                              void* d_out, int out_size, void* d_ws, size_t ws_size,
                              hipStream_t stream)
{
    const float* X  = (const float*)d_in[0];
    const float* W1 = (const float*)d_in[1];
    const float* B1 = (const float*)d_in[2];
    const float* W2 = (const float*)d_in[3];
    const float* B2 = (const float*)d_in[4];
    const float* LS = (const float*)d_in[5];
    const float* LB = (const float*)d_in[6];

    float* out  = (float*)d_out;
    float* Zo   = out;
    float* loss = out + (size_t)NTOK * DPRJ;
    float* Lg   = loss + 1;

    char* ws = (char*)d_ws;
    ushort* Hh   = (ushort*)(ws);                 //  8,388,608
    ushort* Hl   = (ushort*)(ws + 8388608);       //  8,388,608
    ushort* W1tH = (ushort*)(ws + 16777216);      //  2,097,152 (dead after g1)
    ushort* W1tL = (ushort*)(ws + 18874368);      //  2,097,152 (dead after g1)
    float*  P    = (float*) (ws + 16777216);      //  8,388,608 (aliases W1t; written g2)
    ushort* W2tH = (ushort*)(ws + 25165824);      //    524,288
    ushort* W2tL = (ushort*)(ws + 25690112);      //    524,288
    ushort* Zbh  = (ushort*)(ws + 26214400);      //  2,097,152
    ushort* Zbl  = (ushort*)(ws + 28311552);      //  2,097,152
    double* acc  = (double*)(ws + 30408704);      //          8

    k_cvt_T <<<dim3(32, 32),    256, 0, stream>>>(W1, W1tH, W1tL, DEMB, DHID);
    k_cvt_T <<<dim3(8, 32),     256, 0, stream>>>(W2, W2tH, W2tL, DHID, DPRJ);
    k_gemm1 <<<dim3(32, 16),    256, 0, stream>>>(X, W1tH, W1tL, B1, Hh, Hl);
    k_gemm2 <<<dim3(32, 4, 2),  256, 0, stream>>>(Hh, Hl, W2tH, W2tL, P);
    k_norm  <<<dim3(4096),      256, 0, stream>>>(P, B2, Zo, Zbh, Zbl, acc);
    k_gemm3 <<<dim3(32, 32),    256, 0, stream>>>(Zbh, Zbl, LS, LB, Lg, acc);
    k_finalize<<<1, 1, 0, stream>>>(acc, loss);
}

// Round 6
// 231.220 us; speedup vs baseline: 1.1547x; 1.1547x over previous
//
#include <hip/hip_runtime.h>
#include <math.h>

// B=256, A=16 -> N=4096 tokens; EMBED=HIDDEN=1024, PROJ=256.
// fp32 GEMMs emulated via bf16 hi/lo split MFMA (3 terms: Ah*Bh + Ah*Bl + Al*Bh).
// k-chunk-major LDS [kb][row][8] (conflict-free b128, linear), global_load_lds
// width-16 staging, double-buffered 2-phase pipeline.
// This round: loss via per-block float partials + tree reduce (NO double atomic
// CAS storm); logit stores plain (NO nontemporal -> L2 write-combining).
// d_out: z [4096*256] | loss [1] | logits [4096*4096]  (fp32)
// d_ws layout (30,412,800 B; aliased lifetimes disjoint):
//   [0,8M) Hh | [8M,16M) Hl | [16M,20M) W1t (dead after g1) / [16M,24M) P
//   | [24M..25M) W2t | [25M,27M) Zbh | [27M,29M) Zbl | partial[1024] f32

#define NTOK 4096
#define DEMB 1024
#define DHID 1024
#define DPRJ 256

typedef __attribute__((ext_vector_type(8))) short bf16x8;
typedef __attribute__((ext_vector_type(4))) float f32x4;

typedef __attribute__((address_space(3))) void lds_void_t;
typedef __attribute__((address_space(1))) const void gbl_void_t;

static __device__ __forceinline__ void glds16(const void* g, void* l) {
    __builtin_amdgcn_global_load_lds((gbl_void_t*)g, (lds_void_t*)l, 16, 0, 0);
}

// truncating hi/lo bf16 split: v ~= hi + lo, residual ~2^-16 relative
static __device__ __forceinline__ void split2(float v, ushort* h, ushort* l) {
    const uint u = __float_as_uint(v);
    *h = (ushort)(u >> 16);
    const float r = v - __uint_as_float(u & 0xffff0000u);
    *l = (ushort)(__float_as_uint(r) >> 16);
}
// exact-GELU via A&S 7.1.26 rational erf (|err| <= 1.5e-7), hardware exp
static __device__ __forceinline__ float gelu_fast(float v) {
    const float x  = v * 0.70710678118654752440f;
    const float ax = fabsf(x);
    const float t  = 1.0f / (1.0f + 0.3275911f * ax);
    const float poly = t * (0.254829592f + t * (-0.284496736f + t * (1.421413741f
                     + t * (-1.453152027f + t * 1.061405429f))));
    const float erf_ax = 1.0f - poly * __expf(-ax * ax);
    return 0.5f * v * (1.0f + copysignf(erf_ax, x));
}
static __device__ __forceinline__ float log_sigmoid_fast(float x) {
    return fminf(x, 0.0f) - __logf(1.0f + __expf(-fabsf(x)));
}

// ---------------------------------------------------------------------------
// Tiled transpose+convert: fp32 [K][N] -> bf16 hi/lo [N][K]. 32x32 tiles.
// ---------------------------------------------------------------------------
__global__ __launch_bounds__(256)
void k_cvt_T(const float* __restrict__ W, ushort* __restrict__ WtH,
             ushort* __restrict__ WtL, int K, int N)
{
    __shared__ float tile[32][33];
    const int tn0 = blockIdx.x * 32;
    const int tk0 = blockIdx.y * 32;
    const int tr = threadIdx.x >> 5;
    const int tc = threadIdx.x & 31;
#pragma unroll
    for (int p = 0; p < 4; ++p)
        tile[tr + 8 * p][tc] = W[(size_t)(tk0 + tr + 8 * p) * N + tn0 + tc];
    __syncthreads();
#pragma unroll
    for (int p = 0; p < 4; ++p) {
        const int n = tr + 8 * p;
        ushort h, l;
        split2(tile[tc][n], &h, &l);
        WtH[(size_t)(tn0 + n) * K + tk0 + tc] = h;
        WtL[(size_t)(tn0 + n) * K + tk0 + tc] = l;
    }
}

// ---------------------------------------------------------------------------
// GEMM1: H = gelu(X @ W1 + b1) -> bf16 hi/lo.  BM=128, BN=64, BK=32, grid 512.
// LDS buffer (u16): Ah[4][128][8] | Al | Bh[4][64][8] | Bl  = 12288 u16, x2 dbuf.
// A: fp32 reg-load early -> convert -> ds_write late.  B: global_load_lds.
// ---------------------------------------------------------------------------
#define G1_BUF 12288
__global__ __launch_bounds__(256, 3)
void k_gemm1(const float* __restrict__ X,
             const ushort* __restrict__ W1tH, const ushort* __restrict__ W1tL,
             const float* __restrict__ B1,
             ushort* __restrict__ Hh, ushort* __restrict__ Hl)
{
    __shared__ __align__(16) ushort sm[2 * G1_BUF];
    const int t = threadIdx.x, lane = t & 63, w = t >> 6;
    const int wr = w >> 1, wc = w & 1;
    const int bm = blockIdx.x * 128, bn = blockIdx.y * 64;
    const int kb = lane >> 4, lr = lane & 15;

    const int ar = t & 63;
    const float* xp0 = X + (size_t)(bm + ar) * DEMB + w * 8;
    const float* xp1 = xp0 + (size_t)64 * DEMB;
    const ushort* bhs = W1tH + (size_t)(bn + lane) * DEMB + w * 8;
    const ushort* bls = W1tL + (size_t)(bn + lane) * DEMB + w * 8;

    f32x4 acc[4][2];
#pragma unroll
    for (int i = 0; i < 4; ++i)
#pragma unroll
        for (int j = 0; j < 2; ++j) acc[i][j] = (f32x4){0.f, 0.f, 0.f, 0.f};

    {
        const float4 a00 = *(const float4*)(xp0);
        const float4 a01 = *(const float4*)(xp0 + 4);
        const float4 a10 = *(const float4*)(xp1);
        const float4 a11 = *(const float4*)(xp1 + 4);
        glds16(bhs, sm + 8192 + w * 512);
        glds16(bls, sm + 10240 + w * 512);
        const float va[8] = {a00.x, a00.y, a00.z, a00.w, a01.x, a01.y, a01.z, a01.w};
        const float vb[8] = {a10.x, a10.y, a10.z, a10.w, a11.x, a11.y, a11.z, a11.w};
        uint4 h0, l0, h1, l1;
#pragma unroll
        for (int e = 0; e < 8; ++e) {
            split2(va[e], (ushort*)&h0 + e, (ushort*)&l0 + e);
            split2(vb[e], (ushort*)&h1 + e, (ushort*)&l1 + e);
        }
        *(uint4*)(sm + w * 1024 + ar * 8)               = h0;
        *(uint4*)(sm + 4096 + w * 1024 + ar * 8)        = l0;
        *(uint4*)(sm + w * 1024 + (ar + 64) * 8)        = h1;
        *(uint4*)(sm + 4096 + w * 1024 + (ar + 64) * 8) = l1;
        __syncthreads();
    }

    int co = 0;
#pragma unroll 2
    for (int ks = 0; ks < 32; ++ks) {
        float4 a00, a01, a10, a11;
        if (ks < 31) {
            const int kt = (ks + 1) * 32;
            a00 = *(const float4*)(xp0 + kt);
            a01 = *(const float4*)(xp0 + kt + 4);
            a10 = *(const float4*)(xp1 + kt);
            a11 = *(const float4*)(xp1 + kt + 4);
            ushort* nb = sm + (co ^ G1_BUF);
            glds16(bhs + kt, nb + 8192 + w * 512);
            glds16(bls + kt, nb + 10240 + w * 512);
        }
        const ushort* cb = sm + co;
        bf16x8 bh[2], bl[2];
#pragma unroll
        for (int j = 0; j < 2; ++j) {
            const int o = kb * 512 + (wc * 32 + j * 16 + lr) * 8;
            bh[j] = *(const bf16x8*)(cb + 8192 + o);
            bl[j] = *(const bf16x8*)(cb + 10240 + o);
        }
#pragma unroll
        for (int i = 0; i < 4; ++i) {
            const int o = kb * 1024 + (wr * 64 + i * 16 + lr) * 8;
            const bf16x8 ah = *(const bf16x8*)(cb + o);
            const bf16x8 al = *(const bf16x8*)(cb + 4096 + o);
#pragma unroll
            for (int j = 0; j < 2; ++j) {
                acc[i][j] = __builtin_amdgcn_mfma_f32_16x16x32_bf16(ah, bh[j], acc[i][j], 0, 0, 0);
                acc[i][j] = __builtin_amdgcn_mfma_f32_16x16x32_bf16(ah, bl[j], acc[i][j], 0, 0, 0);
                acc[i][j] = __builtin_amdgcn_mfma_f32_16x16x32_bf16(al, bh[j], acc[i][j], 0, 0, 0);
            }
        }
        if (ks < 31) {
            ushort* nb = sm + (co ^ G1_BUF);
            const float va[8] = {a00.x, a00.y, a00.z, a00.w, a01.x, a01.y, a01.z, a01.w};
            const float vb[8] = {a10.x, a10.y, a10.z, a10.w, a11.x, a11.y, a11.z, a11.w};
            uint4 h0, l0, h1, l1;
#pragma unroll
            for (int e = 0; e < 8; ++e) {
                split2(va[e], (ushort*)&h0 + e, (ushort*)&l0 + e);
                split2(vb[e], (ushort*)&h1 + e, (ushort*)&l1 + e);
            }
            *(uint4*)(nb + w * 1024 + ar * 8)               = h0;
            *(uint4*)(nb + 4096 + w * 1024 + ar * 8)        = l0;
            *(uint4*)(nb + w * 1024 + (ar + 64) * 8)        = h1;
            *(uint4*)(nb + 4096 + w * 1024 + (ar + 64) * 8) = l1;
        }
        __syncthreads();
        co ^= G1_BUF;
    }

#pragma unroll
    for (int j = 0; j < 2; ++j) {
        const int col = bn + wc * 32 + j * 16 + lr;
        const float b = B1[col];
#pragma unroll
        for (int i = 0; i < 4; ++i) {
#pragma unroll
            for (int e = 0; e < 4; ++e) {
                const int row = bm + wr * 64 + i * 16 + kb * 4 + e;
                const float g = gelu_fast(acc[i][j][e] + b);
                ushort h, l;
                split2(g, &h, &l);
                Hh[(size_t)row * DHID + col] = h;
                Hl[(size_t)row * DHID + col] = l;
            }
        }
    }
}

// ---------------------------------------------------------------------------
// GEMM2 (split-K x2): P[kz] = H @ W2 over K-half. BM=128, BN=64, grid 256.
// ---------------------------------------------------------------------------
#define G2_BUF 12288
__global__ __launch_bounds__(256, 3)
void k_gemm2(const ushort* __restrict__ Hh, const ushort* __restrict__ Hl,
             const ushort* __restrict__ W2tH, const ushort* __restrict__ W2tL,
             float* __restrict__ P)
{
    __shared__ __align__(16) ushort sm[2 * G2_BUF];
    const int t = threadIdx.x, lane = t & 63, w = t >> 6;
    const int wr = w >> 1, wc = w & 1;
    const int bm = blockIdx.x * 128, bn = blockIdx.y * 64;
    const int k0 = blockIdx.z * 512;
    const int kb = lane >> 4, lr = lane & 15;

    const ushort* ah0 = Hh + (size_t)(bm + lane) * DHID + k0 + w * 8;
    const ushort* ah1 = Hh + (size_t)(bm + 64 + lane) * DHID + k0 + w * 8;
    const ushort* al0 = Hl + (size_t)(bm + lane) * DHID + k0 + w * 8;
    const ushort* al1 = Hl + (size_t)(bm + 64 + lane) * DHID + k0 + w * 8;
    const ushort* bhs = W2tH + (size_t)(bn + lane) * DHID + k0 + w * 8;
    const ushort* bls = W2tL + (size_t)(bn + lane) * DHID + k0 + w * 8;

    f32x4 acc[4][2];
#pragma unroll
    for (int i = 0; i < 4; ++i)
#pragma unroll
        for (int j = 0; j < 2; ++j) acc[i][j] = (f32x4){0.f, 0.f, 0.f, 0.f};

#define G2_STAGE(buf, kt)                                   \
    glds16(ah0 + (kt), (buf) + w * 1024);                   \
    glds16(ah1 + (kt), (buf) + w * 1024 + 512);             \
    glds16(al0 + (kt), (buf) + 4096 + w * 1024);            \
    glds16(al1 + (kt), (buf) + 4096 + w * 1024 + 512);      \
    glds16(bhs + (kt), (buf) + 8192 + w * 512);             \
    glds16(bls + (kt), (buf) + 10240 + w * 512);

    { G2_STAGE(sm, 0); __syncthreads(); }

    int co = 0;
#pragma unroll 2
    for (int ks = 0; ks < 16; ++ks) {
        if (ks < 15) {
            ushort* nb = sm + (co ^ G2_BUF);
            const int kt = (ks + 1) * 32;
            G2_STAGE(nb, kt);
        }
        const ushort* cb = sm + co;
        bf16x8 bh[2], bl[2];
#pragma unroll
        for (int j = 0; j < 2; ++j) {
            const int o = kb * 512 + (wc * 32 + j * 16 + lr) * 8;
            bh[j] = *(const bf16x8*)(cb + 8192 + o);
            bl[j] = *(const bf16x8*)(cb + 10240 + o);
        }
#pragma unroll
        for (int i = 0; i < 4; ++i) {
            const int o = kb * 1024 + (wr * 64 + i * 16 + lr) * 8;
            const bf16x8 ah = *(const bf16x8*)(cb + o);
            const bf16x8 al = *(const bf16x8*)(cb + 4096 + o);
#pragma unroll
            for (int j = 0; j < 2; ++j) {
                acc[i][j] = __builtin_amdgcn_mfma_f32_16x16x32_bf16(ah, bh[j], acc[i][j], 0, 0, 0);
                acc[i][j] = __builtin_amdgcn_mfma_f32_16x16x32_bf16(ah, bl[j], acc[i][j], 0, 0, 0);
                acc[i][j] = __builtin_amdgcn_mfma_f32_16x16x32_bf16(al, bh[j], acc[i][j], 0, 0, 0);
            }
        }
        __syncthreads();
        co ^= G2_BUF;
    }

    float* Pz = P + (size_t)blockIdx.z * NTOK * DPRJ;
#pragma unroll
    for (int j = 0; j < 2; ++j) {
        const int col = bn + wc * 32 + j * 16 + lr;
#pragma unroll
        for (int i = 0; i < 4; ++i) {
#pragma unroll
            for (int e = 0; e < 4; ++e) {
                const int row = bm + wr * 64 + i * 16 + kb * 4 + e;
                Pz[(size_t)row * DPRJ + col] = acc[i][j][e];
            }
        }
    }
}

// ---------------------------------------------------------------------------
// Row normalize: p = P0+P1+b2; z = p/||p||. Emits z fp32 + bf16 hi/lo.
// ---------------------------------------------------------------------------
__global__ __launch_bounds__(256)
void k_norm(const float* __restrict__ P, const float* __restrict__ B2,
            float* __restrict__ Zo, ushort* __restrict__ Zbh,
            ushort* __restrict__ Zbl)
{
    const int r = blockIdx.x;
    const int c = threadIdx.x;

    const float v = P[(size_t)r * DPRJ + c]
                  + P[(size_t)NTOK * DPRJ + (size_t)r * DPRJ + c] + B2[c];
    float ss = v * v;
#pragma unroll
    for (int o = 32; o > 0; o >>= 1) ss += __shfl_down(ss, o);
    __shared__ float wsum[4];
    if ((c & 63) == 0) wsum[c >> 6] = ss;
    __syncthreads();
    const float tot = wsum[0] + wsum[1] + wsum[2] + wsum[3];
    const float z = v / sqrtf(tot);
    Zo[(size_t)r * DPRJ + c] = z;
    ushort h, l;
    split2(z, &h, &l);
    Zbh[(size_t)r * DPRJ + c] = h;
    Zbl[(size_t)r * DPRJ + c] = l;
}

// ---------------------------------------------------------------------------
// GEMM3: logits = (Z @ Z^T)*scale + bias, fused fast log-sigmoid loss.
// BM=BN=128, K=256 (8 k-steps), grid 1024. Plain stores; per-block partial.
// ---------------------------------------------------------------------------
#define G3_BUF 16384
__global__ __launch_bounds__(256, 2)
void k_gemm3(const ushort* __restrict__ Zbh, const ushort* __restrict__ Zbl,
             const float* __restrict__ LS, const float* __restrict__ LB,
             float* __restrict__ Lg, float* __restrict__ partial)
{
    __shared__ __align__(16) ushort sm[2 * G3_BUF];   // 64 KB
    const int t = threadIdx.x, lane = t & 63, w = t >> 6;
    const int wr = w >> 1, wc = w & 1;
    const int bm = blockIdx.x * 128, bn = blockIdx.y * 128;
    const int kb = lane >> 4, lr = lane & 15;

    const ushort* aH0 = Zbh + (size_t)(bm + lane) * DPRJ + w * 8;
    const ushort* aH1 = Zbh + (size_t)(bm + 64 + lane) * DPRJ + w * 8;
    const ushort* aL0 = Zbl + (size_t)(bm + lane) * DPRJ + w * 8;
    const ushort* aL1 = Zbl + (size_t)(bm + 64 + lane) * DPRJ + w * 8;
    const ushort* bH0 = Zbh + (size_t)(bn + lane) * DPRJ + w * 8;
    const ushort* bH1 = Zbh + (size_t)(bn + 64 + lane) * DPRJ + w * 8;
    const ushort* bL0 = Zbl + (size_t)(bn + lane) * DPRJ + w * 8;
    const ushort* bL1 = Zbl + (size_t)(bn + 64 + lane) * DPRJ + w * 8;

    f32x4 acc[4][4];
#pragma unroll
    for (int i = 0; i < 4; ++i)
#pragma unroll
        for (int j = 0; j < 4; ++j) acc[i][j] = (f32x4){0.f, 0.f, 0.f, 0.f};

#define G3_STAGE(buf, kt)                                    \
    glds16(aH0 + (kt), (buf) + w * 1024);                    \
    glds16(aH1 + (kt), (buf) + w * 1024 + 512);              \
    glds16(aL0 + (kt), (buf) + 4096 + w * 1024);             \
    glds16(aL1 + (kt), (buf) + 4096 + w * 1024 + 512);       \
    glds16(bH0 + (kt), (buf) + 8192 + w * 1024);             \
    glds16(bH1 + (kt), (buf) + 8192 + w * 1024 + 512);       \
    glds16(bL0 + (kt), (buf) + 12288 + w * 1024);            \
    glds16(bL1 + (kt), (buf) + 12288 + w * 1024 + 512);

    { G3_STAGE(sm, 0); __syncthreads(); }

    int co = 0;
#pragma unroll
    for (int ks = 0; ks < 8; ++ks) {
        if (ks < 7) {
            ushort* nb = sm + (co ^ G3_BUF);
            const int kt = (ks + 1) * 32;
            G3_STAGE(nb, kt);
        }
        const ushort* cb = sm + co;
        bf16x8 bh[4], bl[4];
#pragma unroll
        for (int j = 0; j < 4; ++j) {
            const int o = kb * 1024 + (wc * 64 + j * 16 + lr) * 8;
            bh[j] = *(const bf16x8*)(cb + 8192 + o);
            bl[j] = *(const bf16x8*)(cb + 12288 + o);
        }
#pragma unroll
        for (int i = 0; i < 4; ++i) {
            const int o = kb * 1024 + (wr * 64 + i * 16 + lr) * 8;
            const bf16x8 ah = *(const bf16x8*)(cb + o);
            const bf16x8 al = *(const bf16x8*)(cb + 4096 + o);
#pragma unroll
            for (int j = 0; j < 4; ++j) {
                acc[i][j] = __builtin_amdgcn_mfma_f32_16x16x32_bf16(ah, bh[j], acc[i][j], 0, 0, 0);
                acc[i][j] = __builtin_amdgcn_mfma_f32_16x16x32_bf16(ah, bl[j], acc[i][j], 0, 0, 0);
                acc[i][j] = __builtin_amdgcn_mfma_f32_16x16x32_bf16(al, bh[j], acc[i][j], 0, 0, 0);
            }
        }
        __syncthreads();
        co ^= G3_BUF;
    }

    const float scale = __expf(LS[0]);
    const float lbias = LB[0];
    float lsum = 0.0f;
#pragma unroll
    for (int j = 0; j < 4; ++j) {
        const int col = bn + wc * 64 + j * 16 + lr;
        const int cid = col >> 4;
#pragma unroll
        for (int i = 0; i < 4; ++i) {
#pragma unroll
            for (int e = 0; e < 4; ++e) {
                const int row = bm + wr * 64 + i * 16 + kb * 4 + e;
                const float lg = fmaf(acc[i][j][e], scale, lbias);
                Lg[(size_t)row * NTOK + col] = lg;   // plain store -> L2 write-combine
                const float x = ((row >> 4) == cid) ? lg : -lg;
                lsum += log_sigmoid_fast(x);
            }
        }
    }

#pragma unroll
    for (int o = 32; o > 0; o >>= 1) lsum += __shfl_down(lsum, o);
    __shared__ float wsum[4];
    if ((t & 63) == 0) wsum[t >> 6] = lsum;
    __syncthreads();
    if (t == 0)
        partial[blockIdx.y * gridDim.x + blockIdx.x]
            = wsum[0] + wsum[1] + wsum[2] + wsum[3];
}

// ---------------------------------------------------------------------------
// Deterministic tree-reduce of the 1024 block partials.
// ---------------------------------------------------------------------------
__global__ __launch_bounds__(256)
void k_finalize(const float* __restrict__ partial, float* __restrict__ loss_out)
{
    const int t = threadIdx.x;
    double s = (double)partial[t] + (double)partial[t + 256]
             + (double)partial[t + 512] + (double)partial[t + 768];
#pragma unroll
    for (int o = 32; o > 0; o >>= 1) s += __shfl_down(s, o);
    __shared__ double ws4[4];
    if ((t & 63) == 0) ws4[t >> 6] = s;
    __syncthreads();
    if (t == 0)
        loss_out[0] = (float)(-(ws4[0] + ws4[1] + ws4[2] + ws4[3]) / (double)NTOK);
}

// ---------------------------------------------------------------------------
extern "C" void kernel_launch(void* const* d_in, const int* in_sizes, int n_in,
                              void* d_out, int out_size, void* d_ws, size_t ws_size,
                              hipStream_t stream)
{
    const float* X  = (const float*)d_in[0];
    const float* W1 = (const float*)d_in[1];
    const float* B1 = (const float*)d_in[2];
    const float* W2 = (const float*)d_in[3];
    const float* B2 = (const float*)d_in[4];
    const float* LS = (const float*)d_in[5];
    const float* LB = (const float*)d_in[6];

    float* out  = (float*)d_out;
    float* Zo   = out;
    float* loss = out + (size_t)NTOK * DPRJ;
    float* Lg   = loss + 1;

    char* ws = (char*)d_ws;
    ushort* Hh   = (ushort*)(ws);                 //  8,388,608
    ushort* Hl   = (ushort*)(ws + 8388608);       //  8,388,608
    ushort* W1tH = (ushort*)(ws + 16777216);      //  2,097,152 (dead after g1)
    ushort* W1tL = (ushort*)(ws + 18874368);      //  2,097,152 (dead after g1)
    float*  P    = (float*) (ws + 16777216);      //  8,388,608 (aliases W1t; written g2)
    ushort* W2tH = (ushort*)(ws + 25165824);      //    524,288
    ushort* W2tL = (ushort*)(ws + 25690112);      //    524,288
    ushort* Zbh  = (ushort*)(ws + 26214400);      //  2,097,152
    ushort* Zbl  = (ushort*)(ws + 28311552);      //  2,097,152
    float*  part = (float*) (ws + 30408704);      //      4,096

    k_cvt_T <<<dim3(32, 32),    256, 0, stream>>>(W1, W1tH, W1tL, DEMB, DHID);
    k_cvt_T <<<dim3(8, 32),     256, 0, stream>>>(W2, W2tH, W2tL, DHID, DPRJ);
    k_gemm1 <<<dim3(32, 16),    256, 0, stream>>>(X, W1tH, W1tL, B1, Hh, Hl);
    k_gemm2 <<<dim3(32, 4, 2),  256, 0, stream>>>(Hh, Hl, W2tH, W2tL, P);
    k_norm  <<<dim3(4096),      256, 0, stream>>>(P, B2, Zo, Zbh, Zbl);
    k_gemm3 <<<dim3(32, 32),    256, 0, stream>>>(Zbh, Zbl, LS, LB, Lg, part);
    k_finalize<<<1, 256, 0, stream>>>(part, loss);
}

// Round 7
// 223.117 us; speedup vs baseline: 1.1966x; 1.0363x over previous
//
#include <hip/hip_runtime.h>
#include <math.h>

// B=256, A=16 -> N=4096 tokens; EMBED=HIDDEN=1024, PROJ=256.
// fp32 GEMMs emulated via bf16 hi/lo split MFMA (3 terms: Ah*Bh + Ah*Bl + Al*Bh).
// Round 7: k_gemm3 rebuilt around memory-TRANSACTION efficiency:
//   - row-major LDS panels staged with CONTIGUOUS global_load_lds (8 lines/instr,
//     was 64), XOR-chunk swizzle applied on BOTH source and ds_read (rule #21)
//   - 2-phase full-half-K (no barriers inside K-loop), 128KB LDS, 512 thr
//   - epilogue: acc -> padded LDS f32 tile -> lane-contiguous row sweep
//     (256B/instr full-line writes; kills partial-sector RMW)
// gemm1/gemm2/norm/cvt unchanged (isolate the theory).
// d_out: z [4096*256] | loss [1] | logits [4096*4096]  (fp32)
// d_ws layout (30,412,800 B; aliased lifetimes disjoint):
//   [0,8M) Hh | [8M,16M) Hl | [16M,20M) W1t (dead after g1) / [16M,24M) P
//   | [24M..25M) W2t | [25M,27M) Zbh | [27M,29M) Zbl | partial[1024] f32

#define NTOK 4096
#define DEMB 1024
#define DHID 1024
#define DPRJ 256

typedef __attribute__((ext_vector_type(8))) short bf16x8;
typedef __attribute__((ext_vector_type(4))) float f32x4;

typedef __attribute__((address_space(3))) void lds_void_t;
typedef __attribute__((address_space(1))) const void gbl_void_t;

static __device__ __forceinline__ void glds16(const void* g, void* l) {
    __builtin_amdgcn_global_load_lds((gbl_void_t*)g, (lds_void_t*)l, 16, 0, 0);
}

// truncating hi/lo bf16 split: v ~= hi + lo, residual ~2^-16 relative
static __device__ __forceinline__ void split2(float v, ushort* h, ushort* l) {
    const uint u = __float_as_uint(v);
    *h = (ushort)(u >> 16);
    const float r = v - __uint_as_float(u & 0xffff0000u);
    *l = (ushort)(__float_as_uint(r) >> 16);
}
// exact-GELU via A&S 7.1.26 rational erf (|err| <= 1.5e-7), hardware exp
static __device__ __forceinline__ float gelu_fast(float v) {
    const float x  = v * 0.70710678118654752440f;
    const float ax = fabsf(x);
    const float t  = 1.0f / (1.0f + 0.3275911f * ax);
    const float poly = t * (0.254829592f + t * (-0.284496736f + t * (1.421413741f
                     + t * (-1.453152027f + t * 1.061405429f))));
    const float erf_ax = 1.0f - poly * __expf(-ax * ax);
    return 0.5f * v * (1.0f + copysignf(erf_ax, x));
}
static __device__ __forceinline__ float log_sigmoid_fast(float x) {
    return fminf(x, 0.0f) - __logf(1.0f + __expf(-fabsf(x)));
}

// ---------------------------------------------------------------------------
// Tiled transpose+convert: fp32 [K][N] -> bf16 hi/lo [N][K]. 32x32 tiles.
// ---------------------------------------------------------------------------
__global__ __launch_bounds__(256)
void k_cvt_T(const float* __restrict__ W, ushort* __restrict__ WtH,
             ushort* __restrict__ WtL, int K, int N)
{
    __shared__ float tile[32][33];
    const int tn0 = blockIdx.x * 32;
    const int tk0 = blockIdx.y * 32;
    const int tr = threadIdx.x >> 5;
    const int tc = threadIdx.x & 31;
#pragma unroll
    for (int p = 0; p < 4; ++p)
        tile[tr + 8 * p][tc] = W[(size_t)(tk0 + tr + 8 * p) * N + tn0 + tc];
    __syncthreads();
#pragma unroll
    for (int p = 0; p < 4; ++p) {
        const int n = tr + 8 * p;
        ushort h, l;
        split2(tile[tc][n], &h, &l);
        WtH[(size_t)(tn0 + n) * K + tk0 + tc] = h;
        WtL[(size_t)(tn0 + n) * K + tk0 + tc] = l;
    }
}

// ---------------------------------------------------------------------------
// GEMM1: H = gelu(X @ W1 + b1) -> bf16 hi/lo.  BM=128, BN=64, BK=32, grid 512.
// (unchanged this round)
// ---------------------------------------------------------------------------
#define G1_BUF 12288
__global__ __launch_bounds__(256, 3)
void k_gemm1(const float* __restrict__ X,
             const ushort* __restrict__ W1tH, const ushort* __restrict__ W1tL,
             const float* __restrict__ B1,
             ushort* __restrict__ Hh, ushort* __restrict__ Hl)
{
    __shared__ __align__(16) ushort sm[2 * G1_BUF];
    const int t = threadIdx.x, lane = t & 63, w = t >> 6;
    const int wr = w >> 1, wc = w & 1;
    const int bm = blockIdx.x * 128, bn = blockIdx.y * 64;
    const int kb = lane >> 4, lr = lane & 15;

    const int ar = t & 63;
    const float* xp0 = X + (size_t)(bm + ar) * DEMB + w * 8;
    const float* xp1 = xp0 + (size_t)64 * DEMB;
    const ushort* bhs = W1tH + (size_t)(bn + lane) * DEMB + w * 8;
    const ushort* bls = W1tL + (size_t)(bn + lane) * DEMB + w * 8;

    f32x4 acc[4][2];
#pragma unroll
    for (int i = 0; i < 4; ++i)
#pragma unroll
        for (int j = 0; j < 2; ++j) acc[i][j] = (f32x4){0.f, 0.f, 0.f, 0.f};

    {
        const float4 a00 = *(const float4*)(xp0);
        const float4 a01 = *(const float4*)(xp0 + 4);
        const float4 a10 = *(const float4*)(xp1);
        const float4 a11 = *(const float4*)(xp1 + 4);
        glds16(bhs, sm + 8192 + w * 512);
        glds16(bls, sm + 10240 + w * 512);
        const float va[8] = {a00.x, a00.y, a00.z, a00.w, a01.x, a01.y, a01.z, a01.w};
        const float vb[8] = {a10.x, a10.y, a10.z, a10.w, a11.x, a11.y, a11.z, a11.w};
        uint4 h0, l0, h1, l1;
#pragma unroll
        for (int e = 0; e < 8; ++e) {
            split2(va[e], (ushort*)&h0 + e, (ushort*)&l0 + e);
            split2(vb[e], (ushort*)&h1 + e, (ushort*)&l1 + e);
        }
        *(uint4*)(sm + w * 1024 + ar * 8)               = h0;
        *(uint4*)(sm + 4096 + w * 1024 + ar * 8)        = l0;
        *(uint4*)(sm + w * 1024 + (ar + 64) * 8)        = h1;
        *(uint4*)(sm + 4096 + w * 1024 + (ar + 64) * 8) = l1;
        __syncthreads();
    }

    int co = 0;
#pragma unroll 2
    for (int ks = 0; ks < 32; ++ks) {
        float4 a00, a01, a10, a11;
        if (ks < 31) {
            const int kt = (ks + 1) * 32;
            a00 = *(const float4*)(xp0 + kt);
            a01 = *(const float4*)(xp0 + kt + 4);
            a10 = *(const float4*)(xp1 + kt);
            a11 = *(const float4*)(xp1 + kt + 4);
            ushort* nb = sm + (co ^ G1_BUF);
            glds16(bhs + kt, nb + 8192 + w * 512);
            glds16(bls + kt, nb + 10240 + w * 512);
        }
        const ushort* cb = sm + co;
        bf16x8 bh[2], bl[2];
#pragma unroll
        for (int j = 0; j < 2; ++j) {
            const int o = kb * 512 + (wc * 32 + j * 16 + lr) * 8;
            bh[j] = *(const bf16x8*)(cb + 8192 + o);
            bl[j] = *(const bf16x8*)(cb + 10240 + o);
        }
#pragma unroll
        for (int i = 0; i < 4; ++i) {
            const int o = kb * 1024 + (wr * 64 + i * 16 + lr) * 8;
            const bf16x8 ah = *(const bf16x8*)(cb + o);
            const bf16x8 al = *(const bf16x8*)(cb + 4096 + o);
#pragma unroll
            for (int j = 0; j < 2; ++j) {
                acc[i][j] = __builtin_amdgcn_mfma_f32_16x16x32_bf16(ah, bh[j], acc[i][j], 0, 0, 0);
                acc[i][j] = __builtin_amdgcn_mfma_f32_16x16x32_bf16(ah, bl[j], acc[i][j], 0, 0, 0);
                acc[i][j] = __builtin_amdgcn_mfma_f32_16x16x32_bf16(al, bh[j], acc[i][j], 0, 0, 0);
            }
        }
        if (ks < 31) {
            ushort* nb = sm + (co ^ G1_BUF);
            const float va[8] = {a00.x, a00.y, a00.z, a00.w, a01.x, a01.y, a01.z, a01.w};
            const float vb[8] = {a10.x, a10.y, a10.z, a10.w, a11.x, a11.y, a11.z, a11.w};
            uint4 h0, l0, h1, l1;
#pragma unroll
            for (int e = 0; e < 8; ++e) {
                split2(va[e], (ushort*)&h0 + e, (ushort*)&l0 + e);
                split2(vb[e], (ushort*)&h1 + e, (ushort*)&l1 + e);
            }
            *(uint4*)(nb + w * 1024 + ar * 8)               = h0;
            *(uint4*)(nb + 4096 + w * 1024 + ar * 8)        = l0;
            *(uint4*)(nb + w * 1024 + (ar + 64) * 8)        = h1;
            *(uint4*)(nb + 4096 + w * 1024 + (ar + 64) * 8) = l1;
        }
        __syncthreads();
        co ^= G1_BUF;
    }

#pragma unroll
    for (int j = 0; j < 2; ++j) {
        const int col = bn + wc * 32 + j * 16 + lr;
        const float b = B1[col];
#pragma unroll
        for (int i = 0; i < 4; ++i) {
#pragma unroll
            for (int e = 0; e < 4; ++e) {
                const int row = bm + wr * 64 + i * 16 + kb * 4 + e;
                const float g = gelu_fast(acc[i][j][e] + b);
                ushort h, l;
                split2(g, &h, &l);
                Hh[(size_t)row * DHID + col] = h;
                Hl[(size_t)row * DHID + col] = l;
            }
        }
    }
}

// ---------------------------------------------------------------------------
// GEMM2 (split-K x2): P[kz] = H @ W2 over K-half. BM=128, BN=64, grid 256.
// (unchanged this round)
// ---------------------------------------------------------------------------
#define G2_BUF 12288
__global__ __launch_bounds__(256, 3)
void k_gemm2(const ushort* __restrict__ Hh, const ushort* __restrict__ Hl,
             const ushort* __restrict__ W2tH, const ushort* __restrict__ W2tL,
             float* __restrict__ P)
{
    __shared__ __align__(16) ushort sm[2 * G2_BUF];
    const int t = threadIdx.x, lane = t & 63, w = t >> 6;
    const int wr = w >> 1, wc = w & 1;
    const int bm = blockIdx.x * 128, bn = blockIdx.y * 64;
    const int k0 = blockIdx.z * 512;
    const int kb = lane >> 4, lr = lane & 15;

    const ushort* ah0 = Hh + (size_t)(bm + lane) * DHID + k0 + w * 8;
    const ushort* ah1 = Hh + (size_t)(bm + 64 + lane) * DHID + k0 + w * 8;
    const ushort* al0 = Hl + (size_t)(bm + lane) * DHID + k0 + w * 8;
    const ushort* al1 = Hl + (size_t)(bm + 64 + lane) * DHID + k0 + w * 8;
    const ushort* bhs = W2tH + (size_t)(bn + lane) * DHID + k0 + w * 8;
    const ushort* bls = W2tL + (size_t)(bn + lane) * DHID + k0 + w * 8;

    f32x4 acc[4][2];
#pragma unroll
    for (int i = 0; i < 4; ++i)
#pragma unroll
        for (int j = 0; j < 2; ++j) acc[i][j] = (f32x4){0.f, 0.f, 0.f, 0.f};

#define G2_STAGE(buf, kt)                                   \
    glds16(ah0 + (kt), (buf) + w * 1024);                   \
    glds16(ah1 + (kt), (buf) + w * 1024 + 512);             \
    glds16(al0 + (kt), (buf) + 4096 + w * 1024);            \
    glds16(al1 + (kt), (buf) + 4096 + w * 1024 + 512);      \
    glds16(bhs + (kt), (buf) + 8192 + w * 512);             \
    glds16(bls + (kt), (buf) + 10240 + w * 512);

    { G2_STAGE(sm, 0); __syncthreads(); }

    int co = 0;
#pragma unroll 2
    for (int ks = 0; ks < 16; ++ks) {
        if (ks < 15) {
            ushort* nb = sm + (co ^ G2_BUF);
            const int kt = (ks + 1) * 32;
            G2_STAGE(nb, kt);
        }
        const ushort* cb = sm + co;
        bf16x8 bh[2], bl[2];
#pragma unroll
        for (int j = 0; j < 2; ++j) {
            const int o = kb * 512 + (wc * 32 + j * 16 + lr) * 8;
            bh[j] = *(const bf16x8*)(cb + 8192 + o);
            bl[j] = *(const bf16x8*)(cb + 10240 + o);
        }
#pragma unroll
        for (int i = 0; i < 4; ++i) {
            const int o = kb * 1024 + (wr * 64 + i * 16 + lr) * 8;
            const bf16x8 ah = *(const bf16x8*)(cb + o);
            const bf16x8 al = *(const bf16x8*)(cb + 4096 + o);
#pragma unroll
            for (int j = 0; j < 2; ++j) {
                acc[i][j] = __builtin_amdgcn_mfma_f32_16x16x32_bf16(ah, bh[j], acc[i][j], 0, 0, 0);
                acc[i][j] = __builtin_amdgcn_mfma_f32_16x16x32_bf16(ah, bl[j], acc[i][j], 0, 0, 0);
                acc[i][j] = __builtin_amdgcn_mfma_f32_16x16x32_bf16(al, bh[j], acc[i][j], 0, 0, 0);
            }
        }
        __syncthreads();
        co ^= G2_BUF;
    }

    float* Pz = P + (size_t)blockIdx.z * NTOK * DPRJ;
#pragma unroll
    for (int j = 0; j < 2; ++j) {
        const int col = bn + wc * 32 + j * 16 + lr;
#pragma unroll
        for (int i = 0; i < 4; ++i) {
#pragma unroll
            for (int e = 0; e < 4; ++e) {
                const int row = bm + wr * 64 + i * 16 + kb * 4 + e;
                Pz[(size_t)row * DPRJ + col] = acc[i][j][e];
            }
        }
    }
}

// ---------------------------------------------------------------------------
// Row normalize: p = P0+P1+b2; z = p/||p||. Emits z fp32 + bf16 hi/lo.
// ---------------------------------------------------------------------------
__global__ __launch_bounds__(256)
void k_norm(const float* __restrict__ P, const float* __restrict__ B2,
            float* __restrict__ Zo, ushort* __restrict__ Zbh,
            ushort* __restrict__ Zbl)
{
    const int r = blockIdx.x;
    const int c = threadIdx.x;

    const float v = P[(size_t)r * DPRJ + c]
                  + P[(size_t)NTOK * DPRJ + (size_t)r * DPRJ + c] + B2[c];
    float ss = v * v;
#pragma unroll
    for (int o = 32; o > 0; o >>= 1) ss += __shfl_down(ss, o);
    __shared__ float wsum[4];
    if ((c & 63) == 0) wsum[c >> 6] = ss;
    __syncthreads();
    const float tot = wsum[0] + wsum[1] + wsum[2] + wsum[3];
    const float z = v / sqrtf(tot);
    Zo[(size_t)r * DPRJ + c] = z;
    ushort h, l;
    split2(z, &h, &l);
    Zbh[(size_t)r * DPRJ + c] = h;
    Zbl[(size_t)r * DPRJ + c] = l;
}

// ---------------------------------------------------------------------------
// GEMM3: logits = (Z @ Z^T)*scale + bias, fused fast log-sigmoid loss.
// 512 thr / 8 waves (2x4), BM=BN=128, 2 phases of K=128, 128KB LDS.
// Contiguous glds staging (4x256B runs/instr) with XOR-chunk swizzle on
// source AND ds_read. Zero barriers inside a phase's K-loop.
// Epilogue: acc -> LDS f32 [128][132] -> lane-contiguous row sweep.
// ---------------------------------------------------------------------------
__global__ __launch_bounds__(512, 1)
void k_gemm3(const ushort* __restrict__ Zbh, const ushort* __restrict__ Zbl,
             const float* __restrict__ LS, const float* __restrict__ LB,
             float* __restrict__ Lg, float* __restrict__ partial)
{
    __shared__ __align__(16) ushort sm[65536];   // 128 KB
    ushort* Ah = sm;              // [128 rows][128 k] u16, swizzled chunks
    ushort* Al = sm + 16384;
    ushort* Bh = sm + 32768;
    ushort* Bl = sm + 49152;

    const int t = threadIdx.x, lane = t & 63, w = t >> 6;   // 8 waves
    const int wr = w >> 2, wc = w & 3;                      // 2 x 4 wave grid
    const int bm = blockIdx.x * 128, bn = blockIdx.y * 128;
    const int kb = lane >> 4, lr = lane & 15;

    // staging geometry: wave w stages rows w*16..w*16+15 of each panel;
    // instr q covers 4 rows; lane: row = w*16+q*4+(lane>>4 of 16-lane grp? no:)
    //   lane l: row_in_instr = l>>4 (4 rows x 16 chunks), chunk c = l&15.
    // global chunk = c ^ (row & 15)  (inverse-swizzle source; read re-applies)
    const int srow0 = w * 16;

    f32x4 acc[4][2];
#pragma unroll
    for (int i = 0; i < 4; ++i)
#pragma unroll
        for (int j = 0; j < 2; ++j) acc[i][j] = (f32x4){0.f, 0.f, 0.f, 0.f};

    float lsum = 0.0f;

#pragma unroll
    for (int ph = 0; ph < 2; ++ph) {
        const int ko = ph * 128;                 // k-offset (u16 elems)
        if (ph) __syncthreads();                 // phase-0 readers done

        // ---- stage 4 panels x 4 instrs (per wave): contiguous 4x256B runs
#pragma unroll
        for (int q = 0; q < 4; ++q) {
            const int row = srow0 + q * 4 + (lane >> 4);   // per-lane row
            const int gck = (lane & 15) ^ (row & 15);      // source chunk
            const size_t ga = (size_t)(bm + row) * DPRJ + ko + (gck << 3);
            const size_t gb = (size_t)(bn + row) * DPRJ + ko + (gck << 3);
            const int lo = (srow0 + q * 4) * 128;          // wave-uniform LDS base
            glds16(Zbh + ga, Ah + lo);
            glds16(Zbl + ga, Al + lo);
            glds16(Zbh + gb, Bh + lo);
            glds16(Zbl + gb, Bl + lo);
        }
        __syncthreads();                          // drains vmcnt before reads

        // ---- 4 k-steps, no barriers
#pragma unroll
        for (int ks = 0; ks < 4; ++ks) {
            const int g = ks * 4 + kb;            // logical chunk for this frag
            bf16x8 bhf[2], blf[2];
#pragma unroll
            for (int j = 0; j < 2; ++j) {
                const int col = wc * 32 + j * 16 + lr;
                const int o = col * 128 + ((g ^ (col & 15)) << 3);
                bhf[j] = *(const bf16x8*)(Bh + o);
                blf[j] = *(const bf16x8*)(Bl + o);
            }
#pragma unroll
            for (int i = 0; i < 4; ++i) {
                const int row = wr * 64 + i * 16 + lr;
                const int o = row * 128 + ((g ^ (row & 15)) << 3);
                const bf16x8 ah = *(const bf16x8*)(Ah + o);
                const bf16x8 al = *(const bf16x8*)(Al + o);
#pragma unroll
                for (int j = 0; j < 2; ++j) {
                    acc[i][j] = __builtin_amdgcn_mfma_f32_16x16x32_bf16(ah, bhf[j], acc[i][j], 0, 0, 0);
                    acc[i][j] = __builtin_amdgcn_mfma_f32_16x16x32_bf16(ah, blf[j], acc[i][j], 0, 0, 0);
                    acc[i][j] = __builtin_amdgcn_mfma_f32_16x16x32_bf16(al, bhf[j], acc[i][j], 0, 0, 0);
                }
            }
        }
    }

    // ---- epilogue: scale/bias, fused loss, then contiguous write via LDS
    const float scale = __expf(LS[0]);
    const float lbias = LB[0];

    __syncthreads();                              // K-loop reads done; reuse LDS
    float* fT = (float*)sm;                       // [128][132] padded f32 tile
#pragma unroll
    for (int j = 0; j < 2; ++j) {
        const int col = bn + wc * 32 + j * 16 + lr;
        const int cid = col >> 4;
#pragma unroll
        for (int i = 0; i < 4; ++i) {
#pragma unroll
            for (int e = 0; e < 4; ++e) {
                const int rloc = wr * 64 + i * 16 + kb * 4 + e;
                const float lg = fmaf(acc[i][j][e], scale, lbias);
                fT[rloc * 132 + (wc * 32 + j * 16 + lr)] = lg;
                const float x = (((bm + rloc) >> 4) == cid) ? lg : -lg;
                lsum += log_sigmoid_fast(x);
            }
        }
    }
    __syncthreads();

    // row-major sweep: 512 threads x 32 elems; per wave-instr 256B contiguous
#pragma unroll
    for (int q = 0; q < 32; ++q) {
        const int e = q * 512 + t;
        const int row = e >> 7, c = e & 127;
        Lg[(size_t)(bm + row) * NTOK + bn + c] = fT[row * 132 + c];
    }

    // block loss partial
#pragma unroll
    for (int o = 32; o > 0; o >>= 1) lsum += __shfl_down(lsum, o);
    __shared__ float wsum[8];
    if (lane == 0) wsum[w] = lsum;
    __syncthreads();
    if (t == 0) {
        float s = 0.f;
#pragma unroll
        for (int i = 0; i < 8; ++i) s += wsum[i];
        partial[blockIdx.y * gridDim.x + blockIdx.x] = s;
    }
}

// ---------------------------------------------------------------------------
// Deterministic tree-reduce of the 1024 block partials.
// ---------------------------------------------------------------------------
__global__ __launch_bounds__(256)
void k_finalize(const float* __restrict__ partial, float* __restrict__ loss_out)
{
    const int t = threadIdx.x;
    double s = (double)partial[t] + (double)partial[t + 256]
             + (double)partial[t + 512] + (double)partial[t + 768];
#pragma unroll
    for (int o = 32; o > 0; o >>= 1) s += __shfl_down(s, o);
    __shared__ double ws4[4];
    if ((t & 63) == 0) ws4[t >> 6] = s;
    __syncthreads();
    if (t == 0)
        loss_out[0] = (float)(-(ws4[0] + ws4[1] + ws4[2] + ws4[3]) / (double)NTOK);
}

// ---------------------------------------------------------------------------
extern "C" void kernel_launch(void* const* d_in, const int* in_sizes, int n_in,
                              void* d_out, int out_size, void* d_ws, size_t ws_size,
                              hipStream_t stream)
{
    const float* X  = (const float*)d_in[0];
    const float* W1 = (const float*)d_in[1];
    const float* B1 = (const float*)d_in[2];
    const float* W2 = (const float*)d_in[3];
    const float* B2 = (const float*)d_in[4];
    const float* LS = (const float*)d_in[5];
    const float* LB = (const float*)d_in[6];

    float* out  = (float*)d_out;
    float* Zo   = out;
    float* loss = out + (size_t)NTOK * DPRJ;
    float* Lg   = loss + 1;

    char* ws = (char*)d_ws;
    ushort* Hh   = (ushort*)(ws);                 //  8,388,608
    ushort* Hl   = (ushort*)(ws + 8388608);       //  8,388,608
    ushort* W1tH = (ushort*)(ws + 16777216);      //  2,097,152 (dead after g1)
    ushort* W1tL = (ushort*)(ws + 18874368);      //  2,097,152 (dead after g1)
    float*  P    = (float*) (ws + 16777216);      //  8,388,608 (aliases W1t; written g2)
    ushort* W2tH = (ushort*)(ws + 25165824);      //    524,288
    ushort* W2tL = (ushort*)(ws + 25690112);      //    524,288
    ushort* Zbh  = (ushort*)(ws + 26214400);      //  2,097,152
    ushort* Zbl  = (ushort*)(ws + 28311552);      //  2,097,152
    float*  part = (float*) (ws + 30408704);      //      4,096

    k_cvt_T <<<dim3(32, 32),    256, 0, stream>>>(W1, W1tH, W1tL, DEMB, DHID);
    k_cvt_T <<<dim3(8, 32),     256, 0, stream>>>(W2, W2tH, W2tL, DHID, DPRJ);
    k_gemm1 <<<dim3(32, 16),    256, 0, stream>>>(X, W1tH, W1tL, B1, Hh, Hl);
    k_gemm2 <<<dim3(32, 4, 2),  256, 0, stream>>>(Hh, Hl, W2tH, W2tL, P);
    k_norm  <<<dim3(4096),      256, 0, stream>>>(P, B2, Zo, Zbh, Zbl);
    k_gemm3 <<<dim3(32, 32),    512, 0, stream>>>(Zbh, Zbl, LS, LB, Lg, part);
    k_finalize<<<1, 256, 0, stream>>>(part, loss);
}

// Round 8
// 208.120 us; speedup vs baseline: 1.2829x; 1.0721x over previous
//
#include <hip/hip_runtime.h>
#include <math.h>

// B=256, A=16 -> N=4096 tokens; EMBED=HIDDEN=1024, PROJ=256.
// fp32 GEMMs emulated via bf16 hi/lo split MFMA (3 terms: Ah*Bh + Ah*Bl + Al*Bh).
// Round 8: gemm1/gemm2 rebuilt with the round-7-proven gemm3 recipe:
//   contiguous XOR-swizzled global_load_lds staging (4x256B runs/instr),
//   BK=128 single-buffered phases, 512 thr / 8 waves. X pre-split to bf16
//   hi/lo in two sequential halves reusing one 8MB buffer.
// d_out: z [4096*256] | loss [1] | logits [4096*4096]  (fp32)
// d_ws (30,412,800 B; aliased lifetimes disjoint):
//   [0,8M) Hh | [8M,16M) Hl
//   [16M,24M) Xs (halves; dead after gemm1b) / P split-K x2 (gemm2..norm)
//   [24M,28M) W1t (dead after gemm1b) / Zbh+Zbl (norm..gemm3)
//   [28M,29M) W2t | [29M..] partial[1024] f32

#define NTOK 4096
#define DEMB 1024
#define DHID 1024
#define DPRJ 256

typedef __attribute__((ext_vector_type(8))) short bf16x8;
typedef __attribute__((ext_vector_type(4))) float f32x4;

typedef __attribute__((address_space(3))) void lds_void_t;
typedef __attribute__((address_space(1))) const void gbl_void_t;

static __device__ __forceinline__ void glds16(const void* g, void* l) {
    __builtin_amdgcn_global_load_lds((gbl_void_t*)g, (lds_void_t*)l, 16, 0, 0);
}

// truncating hi/lo bf16 split: v ~= hi + lo, residual ~2^-16 relative
static __device__ __forceinline__ void split2(float v, ushort* h, ushort* l) {
    const uint u = __float_as_uint(v);
    *h = (ushort)(u >> 16);
    const float r = v - __uint_as_float(u & 0xffff0000u);
    *l = (ushort)(__float_as_uint(r) >> 16);
}
// exact-GELU via A&S 7.1.26 rational erf (|err| <= 1.5e-7), hardware exp
static __device__ __forceinline__ float gelu_fast(float v) {
    const float x  = v * 0.70710678118654752440f;
    const float ax = fabsf(x);
    const float t  = 1.0f / (1.0f + 0.3275911f * ax);
    const float poly = t * (0.254829592f + t * (-0.284496736f + t * (1.421413741f
                     + t * (-1.453152027f + t * 1.061405429f))));
    const float erf_ax = 1.0f - poly * __expf(-ax * ax);
    return 0.5f * v * (1.0f + copysignf(erf_ax, x));
}
static __device__ __forceinline__ float log_sigmoid_fast(float x) {
    return fminf(x, 0.0f) - __logf(1.0f + __expf(-fabsf(x)));
}

// ---------------------------------------------------------------------------
// Tiled transpose+convert: fp32 [K][N] -> bf16 hi/lo [N][K]. 32x32 tiles.
// ---------------------------------------------------------------------------
__global__ __launch_bounds__(256)
void k_cvt_T(const float* __restrict__ W, ushort* __restrict__ WtH,
             ushort* __restrict__ WtL, int K, int N)
{
    __shared__ float tile[32][33];
    const int tn0 = blockIdx.x * 32;
    const int tk0 = blockIdx.y * 32;
    const int tr = threadIdx.x >> 5;
    const int tc = threadIdx.x & 31;
#pragma unroll
    for (int p = 0; p < 4; ++p)
        tile[tr + 8 * p][tc] = W[(size_t)(tk0 + tr + 8 * p) * N + tn0 + tc];
    __syncthreads();
#pragma unroll
    for (int p = 0; p < 4; ++p) {
        const int n = tr + 8 * p;
        ushort h, l;
        split2(tile[tc][n], &h, &l);
        WtH[(size_t)(tn0 + n) * K + tk0 + tc] = h;
        WtL[(size_t)(tn0 + n) * K + tk0 + tc] = l;
    }
}

// ---------------------------------------------------------------------------
// Row-major hi/lo split: X fp32 [rows*1024] -> Xh, Xl u16 (same layout).
// 8 floats per thread, fully coalesced.
// ---------------------------------------------------------------------------
__global__ __launch_bounds__(256)
void k_cvt_X(const float* __restrict__ X, ushort* __restrict__ Xh,
             ushort* __restrict__ Xl)
{
    const size_t idx = ((size_t)blockIdx.x * 256 + threadIdx.x) * 8;
    const float4 v0 = *(const float4*)(X + idx);
    const float4 v1 = *(const float4*)(X + idx + 4);
    const float vv[8] = {v0.x, v0.y, v0.z, v0.w, v1.x, v1.y, v1.z, v1.w};
    uint4 hv, lv;
#pragma unroll
    for (int e = 0; e < 8; ++e)
        split2(vv[e], (ushort*)&hv + e, (ushort*)&lv + e);
    *(uint4*)(Xh + idx) = hv;
    *(uint4*)(Xl + idx) = lv;
}

// ---------------------------------------------------------------------------
// GEMM1: H = gelu(X @ W1 + b1) -> bf16 hi/lo.
// 512 thr / 8 waves (2x4), BM=128, BN=64, 8 phases of BK=128, 96KB LDS.
// Contiguous swizzled glds staging; 2 barriers/phase; zero barriers in k-loop.
// ---------------------------------------------------------------------------
__global__ __launch_bounds__(512, 1)
void k_gemm1(const ushort* __restrict__ Xh, const ushort* __restrict__ Xl,
             const ushort* __restrict__ W1tH, const ushort* __restrict__ W1tL,
             const float* __restrict__ B1, int bm0,
             ushort* __restrict__ Hh, ushort* __restrict__ Hl)
{
    __shared__ __align__(16) ushort sm[49152];   // 96 KB
    ushort* Ah = sm;              // [128][128] u16, chunk-swizzled
    ushort* Al = sm + 16384;
    ushort* Bh = sm + 32768;      // [64][128]
    ushort* Bl = sm + 40960;

    const int t = threadIdx.x, lane = t & 63, w = t >> 6;
    const int wr = w >> 2, wc = w & 3;           // 2 x 4 wave grid
    const int bmr = blockIdx.x * 128;            // row offset within this half
    const int bn  = blockIdx.y * 64;
    const int kb = lane >> 4, lr = lane & 15;

    f32x4 acc[4];
#pragma unroll
    for (int i = 0; i < 4; ++i) acc[i] = (f32x4){0.f, 0.f, 0.f, 0.f};

    for (int ph = 0; ph < 8; ++ph) {
        const int ko = ph * 128;
        if (ph) __syncthreads();
        // A rows w*16..+15 (4 instr x h/l), B rows w*8..+7 (2 instr x h/l)
#pragma unroll
        for (int q = 0; q < 4; ++q) {
            const int row = w * 16 + q * 4 + (lane >> 4);
            const int gck = (lane & 15) ^ (row & 15);
            const size_t ga = (size_t)(bmr + row) * DEMB + ko + (gck << 3);
            const int lo = (w * 16 + q * 4) * 128;
            glds16(Xh + ga, Ah + lo);
            glds16(Xl + ga, Al + lo);
        }
#pragma unroll
        for (int q = 0; q < 2; ++q) {
            const int row = w * 8 + q * 4 + (lane >> 4);
            const int gck = (lane & 15) ^ (row & 15);
            const size_t gb = (size_t)(bn + row) * DEMB + ko + (gck << 3);
            const int lo = (w * 8 + q * 4) * 128;
            glds16(W1tH + gb, Bh + lo);
            glds16(W1tL + gb, Bl + lo);
        }
        __syncthreads();
#pragma unroll
        for (int ks = 0; ks < 4; ++ks) {
            const int g = ks * 4 + kb;
            const int colL = wc * 16 + lr;
            const int ob = colL * 128 + ((g ^ (colL & 15)) << 3);
            const bf16x8 bh = *(const bf16x8*)(Bh + ob);
            const bf16x8 bl = *(const bf16x8*)(Bl + ob);
#pragma unroll
            for (int i = 0; i < 4; ++i) {
                const int rowL = wr * 64 + i * 16 + lr;
                const int oa = rowL * 128 + ((g ^ (rowL & 15)) << 3);
                const bf16x8 ah = *(const bf16x8*)(Ah + oa);
                const bf16x8 al = *(const bf16x8*)(Al + oa);
                acc[i] = __builtin_amdgcn_mfma_f32_16x16x32_bf16(ah, bh, acc[i], 0, 0, 0);
                acc[i] = __builtin_amdgcn_mfma_f32_16x16x32_bf16(ah, bl, acc[i], 0, 0, 0);
                acc[i] = __builtin_amdgcn_mfma_f32_16x16x32_bf16(al, bh, acc[i], 0, 0, 0);
            }
        }
    }

    const int col = bn + wc * 16 + lr;
    const float b = B1[col];
#pragma unroll
    for (int i = 0; i < 4; ++i) {
#pragma unroll
        for (int e = 0; e < 4; ++e) {
            const int row = bm0 + bmr + wr * 64 + i * 16 + kb * 4 + e;
            const float g = gelu_fast(acc[i][e] + b);
            ushort h, l;
            split2(g, &h, &l);
            Hh[(size_t)row * DHID + col] = h;
            Hl[(size_t)row * DHID + col] = l;
        }
    }
}

// ---------------------------------------------------------------------------
// GEMM2 (split-K x2): P[z] = H @ W2 over K-half. Same structure, 4 phases.
// ---------------------------------------------------------------------------
__global__ __launch_bounds__(512, 1)
void k_gemm2(const ushort* __restrict__ Hh, const ushort* __restrict__ Hl,
             const ushort* __restrict__ W2tH, const ushort* __restrict__ W2tL,
             float* __restrict__ P)
{
    __shared__ __align__(16) ushort sm[49152];
    ushort* Ah = sm;
    ushort* Al = sm + 16384;
    ushort* Bh = sm + 32768;
    ushort* Bl = sm + 40960;

    const int t = threadIdx.x, lane = t & 63, w = t >> 6;
    const int wr = w >> 2, wc = w & 3;
    const int bmr = blockIdx.x * 128;
    const int bn  = blockIdx.y * 64;
    const int k0  = blockIdx.z * 512;
    const int kb = lane >> 4, lr = lane & 15;

    f32x4 acc[4];
#pragma unroll
    for (int i = 0; i < 4; ++i) acc[i] = (f32x4){0.f, 0.f, 0.f, 0.f};

    for (int ph = 0; ph < 4; ++ph) {
        const int ko = k0 + ph * 128;
        if (ph) __syncthreads();
#pragma unroll
        for (int q = 0; q < 4; ++q) {
            const int row = w * 16 + q * 4 + (lane >> 4);
            const int gck = (lane & 15) ^ (row & 15);
            const size_t ga = (size_t)(bmr + row) * DHID + ko + (gck << 3);
            const int lo = (w * 16 + q * 4) * 128;
            glds16(Hh + ga, Ah + lo);
            glds16(Hl + ga, Al + lo);
        }
#pragma unroll
        for (int q = 0; q < 2; ++q) {
            const int row = w * 8 + q * 4 + (lane >> 4);
            const int gck = (lane & 15) ^ (row & 15);
            const size_t gb = (size_t)(bn + row) * DHID + ko + (gck << 3);
            const int lo = (w * 8 + q * 4) * 128;
            glds16(W2tH + gb, Bh + lo);
            glds16(W2tL + gb, Bl + lo);
        }
        __syncthreads();
#pragma unroll
        for (int ks = 0; ks < 4; ++ks) {
            const int g = ks * 4 + kb;
            const int colL = wc * 16 + lr;
            const int ob = colL * 128 + ((g ^ (colL & 15)) << 3);
            const bf16x8 bh = *(const bf16x8*)(Bh + ob);
            const bf16x8 bl = *(const bf16x8*)(Bl + ob);
#pragma unroll
            for (int i = 0; i < 4; ++i) {
                const int rowL = wr * 64 + i * 16 + lr;
                const int oa = rowL * 128 + ((g ^ (rowL & 15)) << 3);
                const bf16x8 ah = *(const bf16x8*)(Ah + oa);
                const bf16x8 al = *(const bf16x8*)(Al + oa);
                acc[i] = __builtin_amdgcn_mfma_f32_16x16x32_bf16(ah, bh, acc[i], 0, 0, 0);
                acc[i] = __builtin_amdgcn_mfma_f32_16x16x32_bf16(ah, bl, acc[i], 0, 0, 0);
                acc[i] = __builtin_amdgcn_mfma_f32_16x16x32_bf16(al, bh, acc[i], 0, 0, 0);
            }
        }
    }

    float* Pz = P + (size_t)blockIdx.z * NTOK * DPRJ;
    const int col = bn + wc * 16 + lr;
#pragma unroll
    for (int i = 0; i < 4; ++i) {
#pragma unroll
        for (int e = 0; e < 4; ++e) {
            const int row = bmr + wr * 64 + i * 16 + kb * 4 + e;
            Pz[(size_t)row * DPRJ + col] = acc[i][e];
        }
    }
}

// ---------------------------------------------------------------------------
// Row normalize: p = P0+P1+b2; z = p/||p||. Emits z fp32 + bf16 hi/lo.
// ---------------------------------------------------------------------------
__global__ __launch_bounds__(256)
void k_norm(const float* __restrict__ P, const float* __restrict__ B2,
            float* __restrict__ Zo, ushort* __restrict__ Zbh,
            ushort* __restrict__ Zbl)
{
    const int r = blockIdx.x;
    const int c = threadIdx.x;

    const float v = P[(size_t)r * DPRJ + c]
                  + P[(size_t)NTOK * DPRJ + (size_t)r * DPRJ + c] + B2[c];
    float ss = v * v;
#pragma unroll
    for (int o = 32; o > 0; o >>= 1) ss += __shfl_down(ss, o);
    __shared__ float wsum[4];
    if ((c & 63) == 0) wsum[c >> 6] = ss;
    __syncthreads();
    const float tot = wsum[0] + wsum[1] + wsum[2] + wsum[3];
    const float z = v / sqrtf(tot);
    Zo[(size_t)r * DPRJ + c] = z;
    ushort h, l;
    split2(z, &h, &l);
    Zbh[(size_t)r * DPRJ + c] = h;
    Zbl[(size_t)r * DPRJ + c] = l;
}

// ---------------------------------------------------------------------------
// GEMM3: logits = (Z @ Z^T)*scale + bias, fused fast log-sigmoid loss.
// (round-7 proven version, unchanged)
// ---------------------------------------------------------------------------
__global__ __launch_bounds__(512, 1)
void k_gemm3(const ushort* __restrict__ Zbh, const ushort* __restrict__ Zbl,
             const float* __restrict__ LS, const float* __restrict__ LB,
             float* __restrict__ Lg, float* __restrict__ partial)
{
    __shared__ __align__(16) ushort sm[65536];   // 128 KB
    ushort* Ah = sm;
    ushort* Al = sm + 16384;
    ushort* Bh = sm + 32768;
    ushort* Bl = sm + 49152;

    const int t = threadIdx.x, lane = t & 63, w = t >> 6;
    const int wr = w >> 2, wc = w & 3;
    const int bm = blockIdx.x * 128, bn = blockIdx.y * 128;
    const int kb = lane >> 4, lr = lane & 15;
    const int srow0 = w * 16;

    f32x4 acc[4][2];
#pragma unroll
    for (int i = 0; i < 4; ++i)
#pragma unroll
        for (int j = 0; j < 2; ++j) acc[i][j] = (f32x4){0.f, 0.f, 0.f, 0.f};

    float lsum = 0.0f;

#pragma unroll
    for (int ph = 0; ph < 2; ++ph) {
        const int ko = ph * 128;
        if (ph) __syncthreads();
#pragma unroll
        for (int q = 0; q < 4; ++q) {
            const int row = srow0 + q * 4 + (lane >> 4);
            const int gck = (lane & 15) ^ (row & 15);
            const size_t ga = (size_t)(bm + row) * DPRJ + ko + (gck << 3);
            const size_t gb = (size_t)(bn + row) * DPRJ + ko + (gck << 3);
            const int lo = (srow0 + q * 4) * 128;
            glds16(Zbh + ga, Ah + lo);
            glds16(Zbl + ga, Al + lo);
            glds16(Zbh + gb, Bh + lo);
            glds16(Zbl + gb, Bl + lo);
        }
        __syncthreads();
#pragma unroll
        for (int ks = 0; ks < 4; ++ks) {
            const int g = ks * 4 + kb;
            bf16x8 bhf[2], blf[2];
#pragma unroll
            for (int j = 0; j < 2; ++j) {
                const int col = wc * 32 + j * 16 + lr;
                const int o = col * 128 + ((g ^ (col & 15)) << 3);
                bhf[j] = *(const bf16x8*)(Bh + o);
                blf[j] = *(const bf16x8*)(Bl + o);
            }
#pragma unroll
            for (int i = 0; i < 4; ++i) {
                const int row = wr * 64 + i * 16 + lr;
                const int o = row * 128 + ((g ^ (row & 15)) << 3);
                const bf16x8 ah = *(const bf16x8*)(Ah + o);
                const bf16x8 al = *(const bf16x8*)(Al + o);
#pragma unroll
                for (int j = 0; j < 2; ++j) {
                    acc[i][j] = __builtin_amdgcn_mfma_f32_16x16x32_bf16(ah, bhf[j], acc[i][j], 0, 0, 0);
                    acc[i][j] = __builtin_amdgcn_mfma_f32_16x16x32_bf16(ah, blf[j], acc[i][j], 0, 0, 0);
                    acc[i][j] = __builtin_amdgcn_mfma_f32_16x16x32_bf16(al, bhf[j], acc[i][j], 0, 0, 0);
                }
            }
        }
    }

    const float scale = __expf(LS[0]);
    const float lbias = LB[0];

    __syncthreads();
    float* fT = (float*)sm;                       // [128][132] padded f32 tile
#pragma unroll
    for (int j = 0; j < 2; ++j) {
        const int col = bn + wc * 32 + j * 16 + lr;
        const int cid = col >> 4;
#pragma unroll
        for (int i = 0; i < 4; ++i) {
#pragma unroll
            for (int e = 0; e < 4; ++e) {
                const int rloc = wr * 64 + i * 16 + kb * 4 + e;
                const float lg = fmaf(acc[i][j][e], scale, lbias);
                fT[rloc * 132 + (wc * 32 + j * 16 + lr)] = lg;
                const float x = (((bm + rloc) >> 4) == cid) ? lg : -lg;
                lsum += log_sigmoid_fast(x);
            }
        }
    }
    __syncthreads();

#pragma unroll
    for (int q = 0; q < 32; ++q) {
        const int e = q * 512 + t;
        const int row = e >> 7, c = e & 127;
        Lg[(size_t)(bm + row) * NTOK + bn + c] = fT[row * 132 + c];
    }

#pragma unroll
    for (int o = 32; o > 0; o >>= 1) lsum += __shfl_down(lsum, o);
    __shared__ float wsum[8];
    if (lane == 0) wsum[w] = lsum;
    __syncthreads();
    if (t == 0) {
        float s = 0.f;
#pragma unroll
        for (int i = 0; i < 8; ++i) s += wsum[i];
        partial[blockIdx.y * gridDim.x + blockIdx.x] = s;
    }
}

// ---------------------------------------------------------------------------
// Deterministic tree-reduce of the 1024 block partials.
// ---------------------------------------------------------------------------
__global__ __launch_bounds__(256)
void k_finalize(const float* __restrict__ partial, float* __restrict__ loss_out)
{
    const int t = threadIdx.x;
    double s = (double)partial[t] + (double)partial[t + 256]
             + (double)partial[t + 512] + (double)partial[t + 768];
#pragma unroll
    for (int o = 32; o > 0; o >>= 1) s += __shfl_down(s, o);
    __shared__ double ws4[4];
    if ((t & 63) == 0) ws4[t >> 6] = s;
    __syncthreads();
    if (t == 0)
        loss_out[0] = (float)(-(ws4[0] + ws4[1] + ws4[2] + ws4[3]) / (double)NTOK);
}

// ---------------------------------------------------------------------------
extern "C" void kernel_launch(void* const* d_in, const int* in_sizes, int n_in,
                              void* d_out, int out_size, void* d_ws, size_t ws_size,
                              hipStream_t stream)
{
    const float* X  = (const float*)d_in[0];
    const float* W1 = (const float*)d_in[1];
    const float* B1 = (const float*)d_in[2];
    const float* W2 = (const float*)d_in[3];
    const float* B2 = (const float*)d_in[4];
    const float* LS = (const float*)d_in[5];
    const float* LB = (const float*)d_in[6];

    float* out  = (float*)d_out;
    float* Zo   = out;
    float* loss = out + (size_t)NTOK * DPRJ;
    float* Lg   = loss + 1;

    char* ws = (char*)d_ws;
    ushort* Hh   = (ushort*)(ws);                 //  8 MiB
    ushort* Hl   = (ushort*)(ws + 8388608);       //  8 MiB
    ushort* Xsh  = (ushort*)(ws + 16777216);      //  4 MiB (half of X, hi)
    ushort* Xsl  = (ushort*)(ws + 20971520);      //  4 MiB (half of X, lo)
    float*  P    = (float*) (ws + 16777216);      //  8 MiB (aliases Xs; gemm2+)
    ushort* W1tH = (ushort*)(ws + 25165824);      //  2 MiB (dead after gemm1b)
    ushort* W1tL = (ushort*)(ws + 27262976);      //  2 MiB (dead after gemm1b)
    ushort* Zbh  = (ushort*)(ws + 25165824);      //  2 MiB (aliases W1tH; norm+)
    ushort* Zbl  = (ushort*)(ws + 27262976);      //  2 MiB (aliases W1tL; norm+)
    ushort* W2tH = (ushort*)(ws + 29360128);      //  512 KiB
    ushort* W2tL = (ushort*)(ws + 29884416);      //  512 KiB
    float*  part = (float*) (ws + 30408704);      //  4 KiB

    k_cvt_T <<<dim3(32, 32),   256, 0, stream>>>(W1, W1tH, W1tL, DEMB, DHID);
    k_cvt_T <<<dim3(8, 32),    256, 0, stream>>>(W2, W2tH, W2tL, DHID, DPRJ);
    // half A: rows 0..2047
    k_cvt_X <<<dim3(1024),     256, 0, stream>>>(X, Xsh, Xsl);
    k_gemm1 <<<dim3(16, 16),   512, 0, stream>>>(Xsh, Xsl, W1tH, W1tL, B1, 0, Hh, Hl);
    // half B: rows 2048..4095 (reuse Xs buffer; stream-ordered)
    k_cvt_X <<<dim3(1024),     256, 0, stream>>>(X + (size_t)2048 * DEMB, Xsh, Xsl);
    k_gemm1 <<<dim3(16, 16),   512, 0, stream>>>(Xsh, Xsl, W1tH, W1tL, B1, 2048, Hh, Hl);

    k_gemm2 <<<dim3(32, 4, 2), 512, 0, stream>>>(Hh, Hl, W2tH, W2tL, P);
    k_norm  <<<dim3(4096),     256, 0, stream>>>(P, B2, Zo, Zbh, Zbl);
    k_gemm3 <<<dim3(32, 32),   512, 0, stream>>>(Zbh, Zbl, LS, LB, Lg, part);
    k_finalize<<<1, 256, 0, stream>>>(part, loss);
}

// Round 9
// 199.916 us; speedup vs baseline: 1.3355x; 1.0410x over previous
//
#include <hip/hip_runtime.h>
#include <math.h>

// B=256, A=16 -> N=4096 tokens; EMBED=HIDDEN=1024, PROJ=256.
// fp32 GEMMs emulated via bf16 hi/lo split MFMA (3 terms: Ah*Bh + Ah*Bl + Al*Bh).
// Round 9:
//  - gemm1/gemm2: BK=64 DOUBLE-BUFFERED phases (stage next || compute cur,
//    one barrier/phase, contiguous XOR-swizzled glds staging)
//  - gemm3: BK=64 single-buffered, 64KB LDS -> 2 blocks/CU; epilogue fT in
//    two 64-row passes (write overlap across resident blocks)
//  - cvt_T W1+W2 fused into one launch
// d_out: z [4096*256] | loss [1] | logits [4096*4096]  (fp32)
// d_ws (30,412,800 B; aliased lifetimes disjoint):
//   [0,8M) Hh | [8M,16M) Hl
//   [16M,24M) Xs halves (dead after gemm1b) / P split-K x2 (gemm2..norm)
//   [24M,28M) W1t (dead after gemm1b) / Zbh+Zbl (norm..gemm3)
//   [28M,29M) W2t | [29M..] partial[1024] f32

#define NTOK 4096
#define DEMB 1024
#define DHID 1024
#define DPRJ 256

typedef __attribute__((ext_vector_type(8))) short bf16x8;
typedef __attribute__((ext_vector_type(4))) float f32x4;

typedef __attribute__((address_space(3))) void lds_void_t;
typedef __attribute__((address_space(1))) const void gbl_void_t;

static __device__ __forceinline__ void glds16(const void* g, void* l) {
    __builtin_amdgcn_global_load_lds((gbl_void_t*)g, (lds_void_t*)l, 16, 0, 0);
}

// truncating hi/lo bf16 split: v ~= hi + lo, residual ~2^-16 relative
static __device__ __forceinline__ void split2(float v, ushort* h, ushort* l) {
    const uint u = __float_as_uint(v);
    *h = (ushort)(u >> 16);
    const float r = v - __uint_as_float(u & 0xffff0000u);
    *l = (ushort)(__float_as_uint(r) >> 16);
}
// exact-GELU via A&S 7.1.26 rational erf (|err| <= 1.5e-7), hardware exp
static __device__ __forceinline__ float gelu_fast(float v) {
    const float x  = v * 0.70710678118654752440f;
    const float ax = fabsf(x);
    const float t  = 1.0f / (1.0f + 0.3275911f * ax);
    const float poly = t * (0.254829592f + t * (-0.284496736f + t * (1.421413741f
                     + t * (-1.453152027f + t * 1.061405429f))));
    const float erf_ax = 1.0f - poly * __expf(-ax * ax);
    return 0.5f * v * (1.0f + copysignf(erf_ax, x));
}
static __device__ __forceinline__ float log_sigmoid_fast(float x) {
    return fminf(x, 0.0f) - __logf(1.0f + __expf(-fabsf(x)));
}

// ---------------------------------------------------------------------------
// Fused transpose+convert for W1 and W2: fp32 [K][N] -> bf16 hi/lo [N][K].
// 1280 blocks: 0..1023 -> W1 (32x32 tiles), 1024..1279 -> W2 (8x32 tiles).
// ---------------------------------------------------------------------------
__global__ __launch_bounds__(256)
void k_cvt_W(const float* __restrict__ W1, ushort* __restrict__ W1tH,
             ushort* __restrict__ W1tL, const float* __restrict__ W2,
             ushort* __restrict__ W2tH, ushort* __restrict__ W2tL)
{
    __shared__ float tile[32][33];
    int id = blockIdx.x;
    const float* W;
    ushort *WtH, *WtL;
    int K, N, tn0, tk0;
    if (id < 1024) {
        W = W1; WtH = W1tH; WtL = W1tL; K = DEMB; N = DHID;
        tn0 = (id & 31) * 32; tk0 = (id >> 5) * 32;
    } else {
        id -= 1024;
        W = W2; WtH = W2tH; WtL = W2tL; K = DHID; N = DPRJ;
        tn0 = (id & 7) * 32; tk0 = (id >> 3) * 32;
    }
    const int tr = threadIdx.x >> 5;
    const int tc = threadIdx.x & 31;
#pragma unroll
    for (int p = 0; p < 4; ++p)
        tile[tr + 8 * p][tc] = W[(size_t)(tk0 + tr + 8 * p) * N + tn0 + tc];
    __syncthreads();
#pragma unroll
    for (int p = 0; p < 4; ++p) {
        const int n = tr + 8 * p;
        ushort h, l;
        split2(tile[tc][n], &h, &l);
        WtH[(size_t)(tn0 + n) * K + tk0 + tc] = h;
        WtL[(size_t)(tn0 + n) * K + tk0 + tc] = l;
    }
}

// ---------------------------------------------------------------------------
// Row-major hi/lo split: X fp32 [rows*1024] -> Xh, Xl u16 (same layout).
// ---------------------------------------------------------------------------
__global__ __launch_bounds__(256)
void k_cvt_X(const float* __restrict__ X, ushort* __restrict__ Xh,
             ushort* __restrict__ Xl)
{
    const size_t idx = ((size_t)blockIdx.x * 256 + threadIdx.x) * 8;
    const float4 v0 = *(const float4*)(X + idx);
    const float4 v1 = *(const float4*)(X + idx + 4);
    const float vv[8] = {v0.x, v0.y, v0.z, v0.w, v1.x, v1.y, v1.z, v1.w};
    uint4 hv, lv;
#pragma unroll
    for (int e = 0; e < 8; ++e)
        split2(vv[e], (ushort*)&hv + e, (ushort*)&lv + e);
    *(uint4*)(Xh + idx) = hv;
    *(uint4*)(Xl + idx) = lv;
}

// ---------------------------------------------------------------------------
// GEMM1: H = gelu(X @ W1 + b1) -> bf16 hi/lo.  Per half: 2048 rows.
// 512 thr / 8 waves (2x4), BM=128, BN=64, 16 phases BK=64, DOUBLE-BUFFERED
// 96KB LDS. Buffer (u16): Ah[128][64] | Al | Bh[64][64] | Bl = 24576 u16.
// ---------------------------------------------------------------------------
#define G1B 24576
__global__ __launch_bounds__(512, 2)
void k_gemm1(const ushort* __restrict__ Xh, const ushort* __restrict__ Xl,
             const ushort* __restrict__ W1tH, const ushort* __restrict__ W1tL,
             const float* __restrict__ B1, int bm0,
             ushort* __restrict__ Hh, ushort* __restrict__ Hl)
{
    __shared__ __align__(16) ushort sm[2 * G1B];
    const int t = threadIdx.x, lane = t & 63, w = t >> 6;
    const int wr = w >> 2, wc = w & 3;
    const int bmr = blockIdx.x * 128, bn = blockIdx.y * 64;
    const int kb = lane >> 4, lr = lane & 15;
    const int srow = lane >> 3, sck = lane & 7;

    f32x4 acc[4];
#pragma unroll
    for (int i = 0; i < 4; ++i) acc[i] = (f32x4){0.f, 0.f, 0.f, 0.f};

#define G1_STAGE(buf, ko)                                                   \
    {                                                                       \
        _Pragma("unroll")                                                   \
        for (int q = 0; q < 2; ++q) {                                       \
            const int row = w * 16 + q * 8 + srow;                          \
            const int gck = sck ^ (row & 7);                                \
            const size_t ga = (size_t)(bmr + row) * DEMB + (ko) + (gck << 3);\
            const int lo = (w * 16 + q * 8) * 64;                           \
            glds16(Xh + ga, (buf) + lo);                                    \
            glds16(Xl + ga, (buf) + 8192 + lo);                             \
        }                                                                   \
        {                                                                   \
            const int row = w * 8 + srow;                                   \
            const int gck = sck ^ (row & 7);                                \
            const size_t gb = (size_t)(bn + row) * DEMB + (ko) + (gck << 3);\
            const int lo = (w * 8) * 64;                                    \
            glds16(W1tH + gb, (buf) + 16384 + lo);                          \
            glds16(W1tL + gb, (buf) + 20480 + lo);                          \
        }                                                                   \
    }

    G1_STAGE(sm, 0);
    __syncthreads();
    int co = 0;
    for (int ph = 0; ph < 16; ++ph) {
        if (ph < 15) { G1_STAGE(sm + (co ^ G1B), (ph + 1) * 64); }
        const ushort* cb = sm + co;
#pragma unroll
        for (int ks = 0; ks < 2; ++ks) {
            const int g = ks * 4 + kb;
            const int col = wc * 16 + lr;
            const int ob = col * 64 + ((g ^ (col & 7)) << 3);
            const bf16x8 bh = *(const bf16x8*)(cb + 16384 + ob);
            const bf16x8 bl = *(const bf16x8*)(cb + 20480 + ob);
#pragma unroll
            for (int i = 0; i < 4; ++i) {
                const int row = wr * 64 + i * 16 + lr;
                const int oa = row * 64 + ((g ^ (row & 7)) << 3);
                const bf16x8 ah = *(const bf16x8*)(cb + oa);
                const bf16x8 al = *(const bf16x8*)(cb + 8192 + oa);
                acc[i] = __builtin_amdgcn_mfma_f32_16x16x32_bf16(ah, bh, acc[i], 0, 0, 0);
                acc[i] = __builtin_amdgcn_mfma_f32_16x16x32_bf16(ah, bl, acc[i], 0, 0, 0);
                acc[i] = __builtin_amdgcn_mfma_f32_16x16x32_bf16(al, bh, acc[i], 0, 0, 0);
            }
        }
        __syncthreads();
        co ^= G1B;
    }

    const int col = bn + wc * 16 + lr;
    const float b = B1[col];
#pragma unroll
    for (int i = 0; i < 4; ++i) {
#pragma unroll
        for (int e = 0; e < 4; ++e) {
            const int row = bm0 + bmr + wr * 64 + i * 16 + kb * 4 + e;
            const float g = gelu_fast(acc[i][e] + b);
            ushort h, l;
            split2(g, &h, &l);
            Hh[(size_t)row * DHID + col] = h;
            Hl[(size_t)row * DHID + col] = l;
        }
    }
}

// ---------------------------------------------------------------------------
// GEMM2 (split-K x2): P[z] = H @ W2 over K-half. Same dbuf structure, 8 phases.
// ---------------------------------------------------------------------------
__global__ __launch_bounds__(512, 2)
void k_gemm2(const ushort* __restrict__ Hh, const ushort* __restrict__ Hl,
             const ushort* __restrict__ W2tH, const ushort* __restrict__ W2tL,
             float* __restrict__ P)
{
    __shared__ __align__(16) ushort sm[2 * G1B];
    const int t = threadIdx.x, lane = t & 63, w = t >> 6;
    const int wr = w >> 2, wc = w & 3;
    const int bmr = blockIdx.x * 128, bn = blockIdx.y * 64;
    const int k0 = blockIdx.z * 512;
    const int kb = lane >> 4, lr = lane & 15;
    const int srow = lane >> 3, sck = lane & 7;

    f32x4 acc[4];
#pragma unroll
    for (int i = 0; i < 4; ++i) acc[i] = (f32x4){0.f, 0.f, 0.f, 0.f};

#define G2_STAGE(buf, ko)                                                   \
    {                                                                       \
        _Pragma("unroll")                                                   \
        for (int q = 0; q < 2; ++q) {                                       \
            const int row = w * 16 + q * 8 + srow;                          \
            const int gck = sck ^ (row & 7);                                \
            const size_t ga = (size_t)(bmr + row) * DHID + (ko) + (gck << 3);\
            const int lo = (w * 16 + q * 8) * 64;                           \
            glds16(Hh + ga, (buf) + lo);                                    \
            glds16(Hl + ga, (buf) + 8192 + lo);                             \
        }                                                                   \
        {                                                                   \
            const int row = w * 8 + srow;                                   \
            const int gck = sck ^ (row & 7);                                \
            const size_t gb = (size_t)(bn + row) * DHID + (ko) + (gck << 3);\
            const int lo = (w * 8) * 64;                                    \
            glds16(W2tH + gb, (buf) + 16384 + lo);                          \
            glds16(W2tL + gb, (buf) + 20480 + lo);                          \
        }                                                                   \
    }

    G2_STAGE(sm, k0);
    __syncthreads();
    int co = 0;
    for (int ph = 0; ph < 8; ++ph) {
        if (ph < 7) { G2_STAGE(sm + (co ^ G1B), k0 + (ph + 1) * 64); }
        const ushort* cb = sm + co;
#pragma unroll
        for (int ks = 0; ks < 2; ++ks) {
            const int g = ks * 4 + kb;
            const int col = wc * 16 + lr;
            const int ob = col * 64 + ((g ^ (col & 7)) << 3);
            const bf16x8 bh = *(const bf16x8*)(cb + 16384 + ob);
            const bf16x8 bl = *(const bf16x8*)(cb + 20480 + ob);
#pragma unroll
            for (int i = 0; i < 4; ++i) {
                const int row = wr * 64 + i * 16 + lr;
                const int oa = row * 64 + ((g ^ (row & 7)) << 3);
                const bf16x8 ah = *(const bf16x8*)(cb + oa);
                const bf16x8 al = *(const bf16x8*)(cb + 8192 + oa);
                acc[i] = __builtin_amdgcn_mfma_f32_16x16x32_bf16(ah, bh, acc[i], 0, 0, 0);
                acc[i] = __builtin_amdgcn_mfma_f32_16x16x32_bf16(ah, bl, acc[i], 0, 0, 0);
                acc[i] = __builtin_amdgcn_mfma_f32_16x16x32_bf16(al, bh, acc[i], 0, 0, 0);
            }
        }
        __syncthreads();
        co ^= G1B;
    }

    float* Pz = P + (size_t)blockIdx.z * NTOK * DPRJ;
    const int col = bn + wc * 16 + lr;
#pragma unroll
    for (int i = 0; i < 4; ++i) {
#pragma unroll
        for (int e = 0; e < 4; ++e) {
            const int row = bmr + wr * 64 + i * 16 + kb * 4 + e;
            Pz[(size_t)row * DPRJ + col] = acc[i][e];
        }
    }
}

// ---------------------------------------------------------------------------
// Row normalize: p = P0+P1+b2; z = p/||p||. Emits z fp32 + bf16 hi/lo.
// ---------------------------------------------------------------------------
__global__ __launch_bounds__(256)
void k_norm(const float* __restrict__ P, const float* __restrict__ B2,
            float* __restrict__ Zo, ushort* __restrict__ Zbh,
            ushort* __restrict__ Zbl)
{
    const int r = blockIdx.x;
    const int c = threadIdx.x;

    const float v = P[(size_t)r * DPRJ + c]
                  + P[(size_t)NTOK * DPRJ + (size_t)r * DPRJ + c] + B2[c];
    float ss = v * v;
#pragma unroll
    for (int o = 32; o > 0; o >>= 1) ss += __shfl_down(ss, o);
    __shared__ float wsum[4];
    if ((c & 63) == 0) wsum[c >> 6] = ss;
    __syncthreads();
    const float tot = wsum[0] + wsum[1] + wsum[2] + wsum[3];
    const float z = v / sqrtf(tot);
    Zo[(size_t)r * DPRJ + c] = z;
    ushort h, l;
    split2(z, &h, &l);
    Zbh[(size_t)r * DPRJ + c] = h;
    Zbl[(size_t)r * DPRJ + c] = l;
}

// ---------------------------------------------------------------------------
// GEMM3: logits = (Z @ Z^T)*scale + bias, fused fast log-sigmoid loss.
// 512 thr / 8 waves (2x4), BM=BN=128, 4 phases BK=64, 64KB LDS -> 2 blk/CU.
// Buffer (u16): Ah[128][64] | Al | Bh[128][64] | Bl = 32768 u16.
// Epilogue: two 64-row fT passes (33KB LDS reuse) + contiguous row sweep.
// ---------------------------------------------------------------------------
__global__ __launch_bounds__(512, 4)
void k_gemm3(const ushort* __restrict__ Zbh, const ushort* __restrict__ Zbl,
             const float* __restrict__ LS, const float* __restrict__ LB,
             float* __restrict__ Lg, float* __restrict__ partial)
{
    __shared__ __align__(16) ushort sm[32768];   // 64 KB
    ushort* Ah = sm;
    ushort* Al = sm + 8192;
    ushort* Bh = sm + 16384;
    ushort* Bl = sm + 24576;

    const int t = threadIdx.x, lane = t & 63, w = t >> 6;
    const int wr = w >> 2, wc = w & 3;
    const int bm = blockIdx.x * 128, bn = blockIdx.y * 128;
    const int kb = lane >> 4, lr = lane & 15;
    const int srow = lane >> 3, sck = lane & 7;

    f32x4 acc[4][2];
#pragma unroll
    for (int i = 0; i < 4; ++i)
#pragma unroll
        for (int j = 0; j < 2; ++j) acc[i][j] = (f32x4){0.f, 0.f, 0.f, 0.f};

    for (int ph = 0; ph < 4; ++ph) {
        const int ko = ph * 64;
        if (ph) __syncthreads();
#pragma unroll
        for (int q = 0; q < 2; ++q) {
            const int row = w * 16 + q * 8 + srow;
            const int gck = sck ^ (row & 7);
            const size_t ga = (size_t)(bm + row) * DPRJ + ko + (gck << 3);
            const size_t gb = (size_t)(bn + row) * DPRJ + ko + (gck << 3);
            const int lo = (w * 16 + q * 8) * 64;
            glds16(Zbh + ga, Ah + lo);
            glds16(Zbl + ga, Al + lo);
            glds16(Zbh + gb, Bh + lo);
            glds16(Zbl + gb, Bl + lo);
        }
        __syncthreads();
#pragma unroll
        for (int ks = 0; ks < 2; ++ks) {
            const int g = ks * 4 + kb;
            bf16x8 bhf[2], blf[2];
#pragma unroll
            for (int j = 0; j < 2; ++j) {
                const int col = wc * 32 + j * 16 + lr;
                const int o = col * 64 + ((g ^ (col & 7)) << 3);
                bhf[j] = *(const bf16x8*)(Bh + o);
                blf[j] = *(const bf16x8*)(Bl + o);
            }
#pragma unroll
            for (int i = 0; i < 4; ++i) {
                const int row = wr * 64 + i * 16 + lr;
                const int o = row * 64 + ((g ^ (row & 7)) << 3);
                const bf16x8 ah = *(const bf16x8*)(Ah + o);
                const bf16x8 al = *(const bf16x8*)(Al + o);
#pragma unroll
                for (int j = 0; j < 2; ++j) {
                    acc[i][j] = __builtin_amdgcn_mfma_f32_16x16x32_bf16(ah, bhf[j], acc[i][j], 0, 0, 0);
                    acc[i][j] = __builtin_amdgcn_mfma_f32_16x16x32_bf16(ah, blf[j], acc[i][j], 0, 0, 0);
                    acc[i][j] = __builtin_amdgcn_mfma_f32_16x16x32_bf16(al, bhf[j], acc[i][j], 0, 0, 0);
                }
            }
        }
    }

    const float scale = __expf(LS[0]);
    const float lbias = LB[0];

    // fused loss over this thread's 32 outputs (register-only)
    float lsum = 0.0f;
#pragma unroll
    for (int j = 0; j < 2; ++j) {
        const int col = bn + wc * 32 + j * 16 + lr;
        const int cid = col >> 4;
#pragma unroll
        for (int i = 0; i < 4; ++i) {
#pragma unroll
            for (int e = 0; e < 4; ++e) {
                const int row = bm + wr * 64 + i * 16 + kb * 4 + e;
                const float lg = fmaf(acc[i][j][e], scale, lbias);
                const float x = ((row >> 4) == cid) ? lg : -lg;
                lsum += log_sigmoid_fast(x);
            }
        }
    }

    // two-pass epilogue through LDS f32 tile [64][132] for full-line writes
    float* fT = (float*)sm;
#pragma unroll
    for (int p = 0; p < 2; ++p) {
        __syncthreads();
        if (wr == p) {
#pragma unroll
            for (int j = 0; j < 2; ++j) {
#pragma unroll
                for (int i = 0; i < 4; ++i) {
#pragma unroll
                    for (int e = 0; e < 4; ++e) {
                        const int rloc = i * 16 + kb * 4 + e;      // 0..63
                        fT[rloc * 132 + (wc * 32 + j * 16 + lr)]
                            = fmaf(acc[i][j][e], scale, lbias);
                    }
                }
            }
        }
        __syncthreads();
#pragma unroll
        for (int q = 0; q < 16; ++q) {
            const int e = q * 512 + t;
            const int row = e >> 7, c = e & 127;
            Lg[(size_t)(bm + p * 64 + row) * NTOK + bn + c] = fT[row * 132 + c];
        }
    }

    // block loss partial
#pragma unroll
    for (int o = 32; o > 0; o >>= 1) lsum += __shfl_down(lsum, o);
    __shared__ float wsum[8];
    if (lane == 0) wsum[w] = lsum;
    __syncthreads();
    if (t == 0) {
        float s = 0.f;
#pragma unroll
        for (int i = 0; i < 8; ++i) s += wsum[i];
        partial[blockIdx.y * gridDim.x + blockIdx.x] = s;
    }
}

// ---------------------------------------------------------------------------
// Deterministic tree-reduce of the 1024 block partials.
// ---------------------------------------------------------------------------
__global__ __launch_bounds__(256)
void k_finalize(const float* __restrict__ partial, float* __restrict__ loss_out)
{
    const int t = threadIdx.x;
    double s = (double)partial[t] + (double)partial[t + 256]
             + (double)partial[t + 512] + (double)partial[t + 768];
#pragma unroll
    for (int o = 32; o > 0; o >>= 1) s += __shfl_down(s, o);
    __shared__ double ws4[4];
    if ((t & 63) == 0) ws4[t >> 6] = s;
    __syncthreads();
    if (t == 0)
        loss_out[0] = (float)(-(ws4[0] + ws4[1] + ws4[2] + ws4[3]) / (double)NTOK);
}

// ---------------------------------------------------------------------------
extern "C" void kernel_launch(void* const* d_in, const int* in_sizes, int n_in,
                              void* d_out, int out_size, void* d_ws, size_t ws_size,
                              hipStream_t stream)
{
    const float* X  = (const float*)d_in[0];
    const float* W1 = (const float*)d_in[1];
    const float* B1 = (const float*)d_in[2];
    const float* W2 = (const float*)d_in[3];
    const float* B2 = (const float*)d_in[4];
    const float* LS = (const float*)d_in[5];
    const float* LB = (const float*)d_in[6];

    float* out  = (float*)d_out;
    float* Zo   = out;
    float* loss = out + (size_t)NTOK * DPRJ;
    float* Lg   = loss + 1;

    char* ws = (char*)d_ws;
    ushort* Hh   = (ushort*)(ws);                 //  8 MiB
    ushort* Hl   = (ushort*)(ws + 8388608);       //  8 MiB
    ushort* Xsh  = (ushort*)(ws + 16777216);      //  4 MiB (half of X, hi)
    ushort* Xsl  = (ushort*)(ws + 20971520);      //  4 MiB (half of X, lo)
    float*  P    = (float*) (ws + 16777216);      //  8 MiB (aliases Xs; gemm2+)
    ushort* W1tH = (ushort*)(ws + 25165824);      //  2 MiB (dead after gemm1b)
    ushort* W1tL = (ushort*)(ws + 27262976);      //  2 MiB (dead after gemm1b)
    ushort* Zbh  = (ushort*)(ws + 25165824);      //  2 MiB (aliases W1tH; norm+)
    ushort* Zbl  = (ushort*)(ws + 27262976);      //  2 MiB (aliases W1tL; norm+)
    ushort* W2tH = (ushort*)(ws + 29360128);      //  512 KiB
    ushort* W2tL = (ushort*)(ws + 29884416);      //  512 KiB
    float*  part = (float*) (ws + 30408704);      //  4 KiB

    k_cvt_W <<<dim3(1280),     256, 0, stream>>>(W1, W1tH, W1tL, W2, W2tH, W2tL);
    // half A: rows 0..2047
    k_cvt_X <<<dim3(1024),     256, 0, stream>>>(X, Xsh, Xsl);
    k_gemm1 <<<dim3(16, 16),   512, 0, stream>>>(Xsh, Xsl, W1tH, W1tL, B1, 0, Hh, Hl);
    // half B: rows 2048..4095 (reuse Xs buffer; stream-ordered)
    k_cvt_X <<<dim3(1024),     256, 0, stream>>>(X + (size_t)2048 * DEMB, Xsh, Xsl);
    k_gemm1 <<<dim3(16, 16),   512, 0, stream>>>(Xsh, Xsl, W1tH, W1tL, B1, 2048, Hh, Hl);

    k_gemm2 <<<dim3(32, 4, 2), 512, 0, stream>>>(Hh, Hl, W2tH, W2tL, P);
    k_norm  <<<dim3(4096),     256, 0, stream>>>(P, B2, Zo, Zbh, Zbl);
    k_gemm3 <<<dim3(32, 32),   512, 0, stream>>>(Zbh, Zbl, LS, LB, Lg, part);
    k_finalize<<<1, 256, 0, stream>>>(part, loss);
}